// Round 1
// baseline (1318.547 us; speedup 1.0000x reference)
//
#include <hip/hip_runtime.h>
#include <cstddef>

// Problem constants: S=8, B=32, D=5, T=30, E=768, H=128, 4H=512.

__device__ __forceinline__ float sigf(float x) { return 1.0f / (1.0f + __expf(-x)); }
__device__ __forceinline__ float tanhf_(float x) { return 1.0f - 2.0f / (__expf(2.0f * x) + 1.0f); }

// ---------------------------------------------------------------------------
// K1: XU[s, n, t, :] = x(s,n,t,:) @ Uall[s] + bU[s]
//   x(s, n=(b*5+d), t, e) = sentence_feat[b, s, d, t, e]
//   M = 4800 rows/stock, K = 768, N = 512.  64x64 tile, 256 thr, 4x4/thread.
// ---------------------------------------------------------------------------
__global__ __launch_bounds__(256) void k1_xu(const float* __restrict__ sent,
                                             const float* __restrict__ U,
                                             const float* __restrict__ bU,
                                             float* __restrict__ XU) {
  const int s = blockIdx.z, mt = blockIdx.x, nt = blockIdx.y;
  const int tid = threadIdx.x;
  __shared__ float As[16][64];  // [k][m]
  __shared__ float Bs[16][64];  // [k][n]

  const int lr = tid >> 2;          // A load: row 0..63
  const int lk = (tid & 3) << 2;    // A load: k base 0,4,8,12
  const int grow = mt * 64 + lr;    // global row in [0,4800)
  const int n = grow / 30, t = grow % 30;
  const int b = n / 5, d = n % 5;
  const float* arow = sent + (size_t)(((b * 8 + s) * 5 + d) * 30 + t) * 768;

  const int bk = tid >> 4;          // B load: k 0..15
  const int bn = (tid & 15) << 2;   // B load: n base
  const float* Ub = U + (size_t)s * 768 * 512 + nt * 64;

  const int m0 = (tid & 15) << 2;
  const int n0 = (tid >> 4) << 2;
  float acc[4][4] = {};

  for (int kt = 0; kt < 768; kt += 16) {
    const float4 av = *(const float4*)(arow + kt + lk);
    const float4 bv = *(const float4*)(Ub + (size_t)(kt + bk) * 512 + bn);
    As[lk + 0][lr] = av.x; As[lk + 1][lr] = av.y; As[lk + 2][lr] = av.z; As[lk + 3][lr] = av.w;
    *(float4*)(&Bs[bk][bn]) = bv;
    __syncthreads();
#pragma unroll
    for (int kk = 0; kk < 16; ++kk) {
      const float4 a = *(const float4*)(&As[kk][m0]);
      const float4 bq = *(const float4*)(&Bs[kk][n0]);
      const float aa[4] = {a.x, a.y, a.z, a.w};
      const float bb[4] = {bq.x, bq.y, bq.z, bq.w};
#pragma unroll
      for (int i = 0; i < 4; ++i)
#pragma unroll
        for (int jj = 0; jj < 4; ++jj) acc[i][jj] += aa[i] * bb[jj];
    }
    __syncthreads();
  }

  const float4 bias = *(const float4*)(bU + s * 512 + nt * 64 + n0);
  const float bb[4] = {bias.x, bias.y, bias.z, bias.w};
#pragma unroll
  for (int i = 0; i < 4; ++i) {
    const int row = mt * 64 + m0 + i;
    float4 o;
    o.x = acc[i][0] + bb[0]; o.y = acc[i][1] + bb[1];
    o.z = acc[i][2] + bb[2]; o.w = acc[i][3] + bb[3];
    *(float4*)(XU + ((size_t)s * 4800 + row) * 512 + nt * 64 + n0) = o;
  }
}

// ---------------------------------------------------------------------------
// K2: time-LSTM recurrence. 8 sequences/block, 256 threads (2 grp x 128 j).
//   g = sigmoid(h@Wall + ball + XU)  split f,i,o,ct (ALL sigmoided)
//   c_s1 = tanh(c@Wd + bd); c_adj = c + c_s1*(tt-1)
//   c2 = f*c_adj + i*ct; h2 = o*tanh(c2); emit o; hn = o at t==len-1.
// ---------------------------------------------------------------------------
__global__ __launch_bounds__(256) void k2_tlstm(const float* __restrict__ Wall,
                                                const float* __restrict__ ball,
                                                const float* __restrict__ Wd,
                                                const float* __restrict__ bd,
                                                const float* __restrict__ XU,
                                                const float* __restrict__ times,
                                                const int* __restrict__ lens,
                                                float* __restrict__ outs,
                                                float* __restrict__ hn) {
  const int s = blockIdx.y;
  const int n0 = blockIdx.x * 8;
  const int tid = threadIdx.x;
  const int j = tid & 127, grp = tid >> 7;
  __shared__ float hsm[8][128];
  __shared__ float csm[8][128];
  __shared__ int smax;
  if (tid == 0) smax = 0;

  int len_[4], tb_[4];
#pragma unroll
  for (int q = 0; q < 4; ++q) {
    hsm[grp * 4 + q][j] = 0.f;
    csm[grp * 4 + q][j] = 0.f;
    const int n = n0 + grp * 4 + q;
    const int b = n / 5, d = n % 5;
    len_[q] = lens[(b * 8 + s) * 5 + d];
    tb_[q] = ((b * 8 + s) * 5 + d) * 30;
  }
  __syncthreads();
  if (j == 0) {
    int mx = len_[0];
    if (len_[1] > mx) mx = len_[1];
    if (len_[2] > mx) mx = len_[2];
    if (len_[3] > mx) mx = len_[3];
    atomicMax(&smax, mx);
  }
  __syncthreads();
  const int maxlen = smax;

  const float* Wds = Wd + (size_t)s * 16384;
  const float* Was = Wall + (size_t)s * 65536;
  const float bdj = bd[s * 128 + j];
  const float bl0 = ball[s * 512 + j];
  const float bl1 = ball[s * 512 + 128 + j];
  const float bl2 = ball[s * 512 + 256 + j];
  const float bl3 = ball[s * 512 + 384 + j];

  for (int t = 0; t < maxlen; ++t) {
    float cs1[4] = {bdj, bdj, bdj, bdj};
    for (int k = 0; k < 128; ++k) {
      const float w = Wds[k * 128 + j];
#pragma unroll
      for (int q = 0; q < 4; ++q) cs1[q] += csm[grp * 4 + q][k] * w;
    }
#pragma unroll
    for (int q = 0; q < 4; ++q) cs1[q] = tanhf_(cs1[q]);

    float g0[4], g1[4], g2[4], g3[4];
#pragma unroll
    for (int q = 0; q < 4; ++q) {
      const float* xu = XU + ((size_t)(s * 160 + n0 + grp * 4 + q) * 30 + t) * 512;
      g0[q] = bl0 + xu[j];
      g1[q] = bl1 + xu[128 + j];
      g2[q] = bl2 + xu[256 + j];
      g3[q] = bl3 + xu[384 + j];
    }
    for (int k = 0; k < 128; ++k) {
      const float w0 = Was[k * 512 + j];
      const float w1 = Was[k * 512 + 128 + j];
      const float w2 = Was[k * 512 + 256 + j];
      const float w3 = Was[k * 512 + 384 + j];
#pragma unroll
      for (int q = 0; q < 4; ++q) {
        const float hk = hsm[grp * 4 + q][k];
        g0[q] += hk * w0; g1[q] += hk * w1; g2[q] += hk * w2; g3[q] += hk * w3;
      }
    }
    __syncthreads();
#pragma unroll
    for (int q = 0; q < 4; ++q) {
      if (t < len_[q]) {
        const int i = grp * 4 + q;
        const int n = n0 + i;
        const float tt = times[tb_[q] + t];
        const float f = sigf(g0[q]);
        const float ii = sigf(g1[q]);
        const float o = sigf(g2[q]);
        const float ct = sigf(g3[q]);
        const float cc = csm[i][j];
        const float cadj = cc + cs1[q] * (tt - 1.f);
        const float c2 = f * cadj + ii * ct;
        const float h2 = o * tanhf_(c2);
        csm[i][j] = c2;
        hsm[i][j] = h2;
        outs[((size_t)(s * 160 + n) * 30 + t) * 128 + j] = o;
        if (t == len_[q] - 1) hn[(size_t)(s * 160 + n) * 128 + j] = o;
      }
    }
    __syncthreads();
  }
}

// ---------------------------------------------------------------------------
// K3: attention 1, one block per (s, n). score_t = tanh(hn@W1+b1 + o_t@W2+b2)@V+bV,
//     masked softmax over t<len, ctx = sum_t w_t * o_t.
// ---------------------------------------------------------------------------
__global__ __launch_bounds__(128) void k3_attn1(const float* __restrict__ W1,
                                                const float* __restrict__ b1,
                                                const float* __restrict__ W2,
                                                const float* __restrict__ b2,
                                                const float* __restrict__ V,
                                                const float* __restrict__ bV,
                                                const float* __restrict__ outs,
                                                const float* __restrict__ hn,
                                                const int* __restrict__ lens,
                                                float* __restrict__ ctx) {
  const int s = blockIdx.y, n = blockIdx.x, j = threadIdx.x;
  const int b = n / 5, d = n % 5;
  const int len = lens[(b * 8 + s) * 5 + d];
  __shared__ float os[30][128];
  __shared__ float hns[128];
  __shared__ float score[30];
  __shared__ float red[2];

  hns[j] = hn[(size_t)(s * 160 + n) * 128 + j];
  const float* og = outs + (size_t)(s * 160 + n) * 30 * 128;
  for (int idx = j; idx < len * 128; idx += 128) (&os[0][0])[idx] = og[idx];
  __syncthreads();

  const float* W1s = W1 + (size_t)s * 16384;
  const float* W2s = W2 + (size_t)s * 16384;
  float u = b1[s * 128 + j] + b2[s * 128 + j];
  for (int k = 0; k < 128; ++k) u += hns[k] * W1s[k * 128 + j];
  const float Vj = V[s * 128 + j];
  const int lane = j & 63, wid = j >> 6;

  for (int t = 0; t < len; ++t) {
    float a = u;
    for (int k = 0; k < 128; ++k) a += os[t][k] * W2s[k * 128 + j];
    float p = tanhf_(a) * Vj;
#pragma unroll
    for (int off = 32; off; off >>= 1) p += __shfl_down(p, off);
    if (lane == 0) red[wid] = p;
    __syncthreads();
    if (j == 0) score[t] = red[0] + red[1] + bV[s];
    __syncthreads();
  }

  float m = -1e30f;
  for (int t = 0; t < len; ++t) m = fmaxf(m, score[t]);
  float sum = 0.f;
  for (int t = 0; t < len; ++t) sum += __expf(score[t] - m);
  float cx = 0.f;
  for (int t = 0; t < len; ++t) cx += __expf(score[t] - m) * os[t][j];
  ctx[(size_t)(s * 160 + n) * 128 + j] = cx / sum;
}

// ---------------------------------------------------------------------------
// K4: standard LSTM over D=5. split order i,f,g,o (tanh on g). 1 block/(s,b).
// ---------------------------------------------------------------------------
__global__ __launch_bounds__(128) void k4_lstm2(const float* __restrict__ Wih,
                                                const float* __restrict__ bih,
                                                const float* __restrict__ Whh,
                                                const float* __restrict__ bhh,
                                                const float* __restrict__ ctx,
                                                float* __restrict__ hsout,
                                                float* __restrict__ hlast) {
  const int s = blockIdx.y, b = blockIdx.x, j = threadIdx.x;
  __shared__ float hsm[128], xt[128];
  hsm[j] = 0.f;
  float c = 0.f;
  const float* Wis = Wih + (size_t)s * 65536;
  const float* Whs = Whh + (size_t)s * 65536;
  const float bi_ = bih[s * 512 + j] + bhh[s * 512 + j];
  const float bf_ = bih[s * 512 + 128 + j] + bhh[s * 512 + 128 + j];
  const float bg_ = bih[s * 512 + 256 + j] + bhh[s * 512 + 256 + j];
  const float bo_ = bih[s * 512 + 384 + j] + bhh[s * 512 + 384 + j];

  for (int d = 0; d < 5; ++d) {
    xt[j] = ctx[(size_t)(s * 160 + b * 5 + d) * 128 + j];
    __syncthreads();
    float gi = bi_, gf = bf_, gg = bg_, go = bo_;
    for (int k = 0; k < 128; ++k) {
      const float xk = xt[k], hk = hsm[k];
      gi += xk * Wis[k * 512 + j] + hk * Whs[k * 512 + j];
      gf += xk * Wis[k * 512 + 128 + j] + hk * Whs[k * 512 + 128 + j];
      gg += xk * Wis[k * 512 + 256 + j] + hk * Whs[k * 512 + 256 + j];
      go += xk * Wis[k * 512 + 384 + j] + hk * Whs[k * 512 + 384 + j];
    }
    const float c2 = sigf(gf) * c + sigf(gi) * tanhf_(gg);
    const float h2 = sigf(go) * tanhf_(c2);
    c = c2;
    __syncthreads();
    hsm[j] = h2;
    hsout[((size_t)(s * 32 + b) * 5 + d) * 128 + j] = h2;
    if (d == 4) hlast[(size_t)(s * 32 + b) * 128 + j] = h2;
    __syncthreads();
  }
}

// ---------------------------------------------------------------------------
// K5: attention 2 (no mask, D=5) + y = relu(ctx2@x1W+x1b)@x2W+x2b. 1 block/(s,b).
// ---------------------------------------------------------------------------
__global__ __launch_bounds__(128) void k5_attn2(const float* __restrict__ W1,
                                                const float* __restrict__ b1,
                                                const float* __restrict__ W2,
                                                const float* __restrict__ b2,
                                                const float* __restrict__ V,
                                                const float* __restrict__ bV,
                                                const float* __restrict__ x1W,
                                                const float* __restrict__ x1b,
                                                const float* __restrict__ x2W,
                                                const float* __restrict__ x2b,
                                                const float* __restrict__ hs,
                                                const float* __restrict__ hlast,
                                                float* __restrict__ y) {
  const int s = blockIdx.y, b = blockIdx.x, j = threadIdx.x;
  __shared__ float hl[128], hsm[5][128], t1[128], cs2[128], sc[5], red[2];
  hl[j] = hlast[(size_t)(s * 32 + b) * 128 + j];
  const float* hsrc = hs + (size_t)(s * 32 + b) * 640;
  for (int idx = j; idx < 640; idx += 128) (&hsm[0][0])[idx] = hsrc[idx];
  __syncthreads();

  const float* W1s = W1 + (size_t)s * 16384;
  const float* W2s = W2 + (size_t)s * 16384;
  float u = b1[s * 128 + j] + b2[s * 128 + j];
  for (int k = 0; k < 128; ++k) u += hl[k] * W1s[k * 128 + j];
  const float Vj = V[s * 128 + j];
  const int lane = j & 63, wid = j >> 6;

  for (int d = 0; d < 5; ++d) {
    float a = u;
    for (int k = 0; k < 128; ++k) a += hsm[d][k] * W2s[k * 128 + j];
    float p = tanhf_(a) * Vj;
#pragma unroll
    for (int off = 32; off; off >>= 1) p += __shfl_down(p, off);
    if (lane == 0) red[wid] = p;
    __syncthreads();
    if (j == 0) sc[d] = red[0] + red[1] + bV[s];
    __syncthreads();
  }

  float m = -1e30f;
  for (int d = 0; d < 5; ++d) m = fmaxf(m, sc[d]);
  float sum = 0.f;
  for (int d = 0; d < 5; ++d) sum += __expf(sc[d] - m);
  float cx = 0.f;
  for (int d = 0; d < 5; ++d) cx += __expf(sc[d] - m) * hsm[d][j];
  cs2[j] = cx / sum;
  __syncthreads();

  float a = x1b[s * 128 + j];
  for (int k = 0; k < 128; ++k) a += cs2[k] * x1W[(size_t)s * 16384 + k * 128 + j];
  t1[j] = fmaxf(a, 0.f);
  __syncthreads();

  if (j < 64) {
    float yy = x2b[s * 64 + j];
    for (int k = 0; k < 128; ++k) yy += t1[k] * x2W[(size_t)(s * 128 + k) * 64 + j];
    y[(size_t)(s * 32 + b) * 64 + j] = yy;
  }
}

// ---------------------------------------------------------------------------
// K6: xs = relu(stock@h1W+h1b)@h2W+h2b; full=[xs, text]; out = tanh(full@hcW+hcb)
// ---------------------------------------------------------------------------
__global__ __launch_bounds__(256) void k6_final(const float* __restrict__ stock,
                                                const float* __restrict__ h1W,
                                                const float* __restrict__ h1b,
                                                const float* __restrict__ h2W,
                                                const float* __restrict__ h2b,
                                                const float* __restrict__ hcW,
                                                const float* __restrict__ hcb,
                                                const float* __restrict__ yws,
                                                float* __restrict__ out) {
  const int tid = threadIdx.x;
  __shared__ float sf[32 * 17];
  __shared__ float hid[32 * 64];
  __shared__ float xs[32 * 32];
  for (int idx = tid; idx < 544; idx += 256) sf[idx] = stock[idx];
  __syncthreads();
  for (int idx = tid; idx < 2048; idx += 256) {
    const int b = idx >> 6, k = idx & 63;
    float a = h1b[k];
    for (int q = 0; q < 17; ++q) a += sf[b * 17 + q] * h1W[q * 64 + k];
    hid[idx] = fmaxf(a, 0.f);
  }
  __syncthreads();
  for (int idx = tid; idx < 1024; idx += 256) {
    const int b = idx >> 5, mm = idx & 31;
    float a = h2b[mm];
    for (int k = 0; k < 64; ++k) a += hid[b * 64 + k] * h2W[k * 32 + mm];
    xs[idx] = a;
  }
  __syncthreads();
  {
    const int b = tid >> 3, o = tid & 7;
    float a = hcb[o];
    for (int c = 0; c < 32; ++c) a += xs[b * 32 + c] * hcW[c * 8 + o];
    for (int c = 32; c < 544; ++c) {
      const int ss = (c - 32) >> 6, k = (c - 32) & 63;
      a += yws[((size_t)ss * 32 + b) * 64 + k] * hcW[c * 8 + o];
    }
    out[tid] = tanhf_(a);
  }
}

// ---------------------------------------------------------------------------
extern "C" void kernel_launch(void* const* d_in, const int* in_sizes, int n_in,
                              void* d_out, int out_size, void* d_ws, size_t ws_size,
                              hipStream_t stream) {
  (void)in_sizes; (void)n_in; (void)out_size; (void)ws_size;
  const float* stock = (const float*)d_in[0];
  const float* sent  = (const float*)d_in[1];
  const float* times = (const float*)d_in[2];
  const int*   lens  = (const int*)d_in[3];
  const float* tlWall = (const float*)d_in[4];
  const float* tlball = (const float*)d_in[5];
  const float* tlUall = (const float*)d_in[6];
  const float* tlbU   = (const float*)d_in[7];
  const float* tlWd   = (const float*)d_in[8];
  const float* tlbd   = (const float*)d_in[9];
  const float* a1W1 = (const float*)d_in[10];
  const float* a1b1 = (const float*)d_in[11];
  const float* a1W2 = (const float*)d_in[12];
  const float* a1b2 = (const float*)d_in[13];
  const float* a1V  = (const float*)d_in[14];
  const float* a1bV = (const float*)d_in[15];
  const float* l2Wih = (const float*)d_in[16];
  const float* l2bih = (const float*)d_in[17];
  const float* l2Whh = (const float*)d_in[18];
  const float* l2bhh = (const float*)d_in[19];
  const float* a2W1 = (const float*)d_in[20];
  const float* a2b1 = (const float*)d_in[21];
  const float* a2W2 = (const float*)d_in[22];
  const float* a2b2 = (const float*)d_in[23];
  const float* a2V  = (const float*)d_in[24];
  const float* a2bV = (const float*)d_in[25];
  const float* x1W  = (const float*)d_in[26];
  const float* x1b  = (const float*)d_in[27];
  const float* x2W  = (const float*)d_in[28];
  const float* x2b  = (const float*)d_in[29];
  const float* h1W  = (const float*)d_in[30];
  const float* h1b  = (const float*)d_in[31];
  const float* h2W  = (const float*)d_in[32];
  const float* h2b  = (const float*)d_in[33];
  const float* hcW  = (const float*)d_in[34];
  const float* hcb  = (const float*)d_in[35];

  float* ws = (float*)d_ws;
  float* XU    = ws;               // 8*160*30*512   = 19,660,800
  float* outs  = XU + 19660800;    // 8*160*30*128   =  4,915,200
  float* hnb   = outs + 4915200;   // 8*160*128      =    163,840
  float* ctx   = hnb + 163840;     // 8*160*128      =    163,840
  float* hsb   = ctx + 163840;     // 8*32*5*128     =    163,840
  float* hlast = hsb + 163840;     // 8*32*128       =     32,768
  float* yb    = hlast + 32768;    // 8*32*64        =     16,384

  k1_xu<<<dim3(75, 8, 8), 256, 0, stream>>>(sent, tlUall, tlbU, XU);
  k2_tlstm<<<dim3(20, 8), 256, 0, stream>>>(tlWall, tlball, tlWd, tlbd, XU, times, lens, outs, hnb);
  k3_attn1<<<dim3(160, 8), 128, 0, stream>>>(a1W1, a1b1, a1W2, a1b2, a1V, a1bV, outs, hnb, lens, ctx);
  k4_lstm2<<<dim3(32, 8), 128, 0, stream>>>(l2Wih, l2bih, l2Whh, l2bhh, ctx, hsb, hlast);
  k5_attn2<<<dim3(32, 8), 128, 0, stream>>>(a2W1, a2b1, a2W2, a2b2, a2V, a2bV, x1W, x1b, x2W, x2b, hsb, hlast, yb);
  k6_final<<<1, 256, 0, stream>>>(stock, h1W, h1b, h2W, h2b, hcW, hcb, yb, (float*)d_out);
}

// Round 2
// 782.268 us; speedup vs baseline: 1.6855x; 1.6855x over previous
//
#include <hip/hip_runtime.h>
#include <cstddef>

// Problem constants: S=8, B=32, D=5, T=30, E=768, H=128, 4H=512.

__device__ __forceinline__ float sigf(float x) { return 1.0f / (1.0f + __expf(-x)); }
__device__ __forceinline__ float tanhf_(float x) { return 1.0f - 2.0f / (__expf(2.0f * x) + 1.0f); }

// ---------------------------------------------------------------------------
// K1: XU[s, n, t, :] = x(s,n,t,:) @ Uall[s] + bU[s]
//   x(s, n=(b*5+d), t, e) = sentence_feat[b, s, d, t, e]
//   M = 4800 rows/stock, K = 768, N = 512.  64x64 tile, 256 thr, 4x4/thread.
// ---------------------------------------------------------------------------
__global__ __launch_bounds__(256) void k1_xu(const float* __restrict__ sent,
                                             const float* __restrict__ U,
                                             const float* __restrict__ bU,
                                             float* __restrict__ XU) {
  const int s = blockIdx.z, mt = blockIdx.x, nt = blockIdx.y;
  const int tid = threadIdx.x;
  __shared__ float As[16][64];  // [k][m]
  __shared__ float Bs[16][64];  // [k][n]

  const int lr = tid >> 2;          // A load: row 0..63
  const int lk = (tid & 3) << 2;    // A load: k base 0,4,8,12
  const int grow = mt * 64 + lr;    // global row in [0,4800)
  const int n = grow / 30, t = grow % 30;
  const int b = n / 5, d = n % 5;
  const float* arow = sent + (size_t)(((b * 8 + s) * 5 + d) * 30 + t) * 768;

  const int bk = tid >> 4;          // B load: k 0..15
  const int bn = (tid & 15) << 2;   // B load: n base
  const float* Ub = U + (size_t)s * 768 * 512 + nt * 64;

  const int m0 = (tid & 15) << 2;
  const int n0 = (tid >> 4) << 2;
  float acc[4][4] = {};

  for (int kt = 0; kt < 768; kt += 16) {
    const float4 av = *(const float4*)(arow + kt + lk);
    const float4 bv = *(const float4*)(Ub + (size_t)(kt + bk) * 512 + bn);
    As[lk + 0][lr] = av.x; As[lk + 1][lr] = av.y; As[lk + 2][lr] = av.z; As[lk + 3][lr] = av.w;
    *(float4*)(&Bs[bk][bn]) = bv;
    __syncthreads();
#pragma unroll
    for (int kk = 0; kk < 16; ++kk) {
      const float4 a = *(const float4*)(&As[kk][m0]);
      const float4 bq = *(const float4*)(&Bs[kk][n0]);
      const float aa[4] = {a.x, a.y, a.z, a.w};
      const float bb[4] = {bq.x, bq.y, bq.z, bq.w};
#pragma unroll
      for (int i = 0; i < 4; ++i)
#pragma unroll
        for (int jj = 0; jj < 4; ++jj) acc[i][jj] += aa[i] * bb[jj];
    }
    __syncthreads();
  }

  const float4 bias = *(const float4*)(bU + s * 512 + nt * 64 + n0);
  const float bb[4] = {bias.x, bias.y, bias.z, bias.w};
#pragma unroll
  for (int i = 0; i < 4; ++i) {
    const int row = mt * 64 + m0 + i;
    float4 o;
    o.x = acc[i][0] + bb[0]; o.y = acc[i][1] + bb[1];
    o.z = acc[i][2] + bb[2]; o.w = acc[i][3] + bb[3];
    *(float4*)(XU + ((size_t)s * 4800 + row) * 512 + nt * 64 + n0) = o;
  }
}

// ---------------------------------------------------------------------------
// K2 v2: weight-stationary time-LSTM recurrence.
//   Grid (32, 8) = 256 blocks (1/CU), 512 threads = 4 k-groups x 128 j.
//   Thread (kg, j) holds Wall[kg*32..+32][{0,1,2,3}*128+j] (128 VGPR) and
//   Wd[kg*32..+32][j] (32 VGPR) in registers for all 30 steps.
//   Per step: phase A = partial k-reductions (h,c broadcast from LDS),
//   write partials to red[][]; barrier; phase B = owner threads reduce 4
//   partials, apply gates, update h/c in LDS, write o; barrier.
//   Gate order: f,i,o,ct (ALL sigmoided). c_adj = c + cs1*(tt-1).
// ---------------------------------------------------------------------------
__global__ __launch_bounds__(512, 2) void k2_tlstm(const float* __restrict__ Wall,
                                                   const float* __restrict__ ball,
                                                   const float* __restrict__ Wd,
                                                   const float* __restrict__ bd,
                                                   const float* __restrict__ XU,
                                                   const float* __restrict__ times,
                                                   const int* __restrict__ lens,
                                                   float* __restrict__ outs,
                                                   float* __restrict__ hn) {
  const int s = blockIdx.y;
  const int bb = blockIdx.x;     // batch index b (block owns d=0..4 of this b)
  const int n0 = bb * 5;
  const int tid = threadIdx.x;
  const int j = tid & 127;
  const int kg = tid >> 7;       // 0..3, k-range [kg*32, kg*32+32)

  __shared__ float hsm[5][128];
  __shared__ float csm[5][128];
  __shared__ float red[20][5][128];  // [gate*4+kg | 16+kg][seq][j]

  for (int idx = tid; idx < 640; idx += 512) {
    (&hsm[0][0])[idx] = 0.f;
    (&csm[0][0])[idx] = 0.f;
  }

  int len_[5];
  int maxlen = 0;
#pragma unroll
  for (int d = 0; d < 5; ++d) {
    len_[d] = lens[(bb * 8 + s) * 5 + d];
    maxlen = max(maxlen, len_[d]);
  }

  // ---- preload weights into registers ----
  float wall_r[32][4];
  float wd_r[32];
  {
    const float* Wb = Wall + (size_t)s * 65536 + (size_t)(kg * 32) * 512 + j;
    const float* Db = Wd + (size_t)s * 16384 + (size_t)(kg * 32) * 128 + j;
#pragma unroll
    for (int kk = 0; kk < 32; ++kk) {
#pragma unroll
      for (int g = 0; g < 4; ++g) wall_r[kk][g] = Wb[kk * 512 + g * 128];
      wd_r[kk] = Db[kk * 128];
    }
  }

  const float bdj = bd[s * 128 + j];
  float blg[4];
#pragma unroll
  for (int g = 0; g < 4; ++g) blg[g] = ball[s * 512 + g * 128 + j];

  // owned cells: seq kg always; seq 4 owned by kg==0
  const int sqA = kg;
  const bool hasB = (kg == 0);
  const float* xuAb = XU + (size_t)(s * 160 + n0 + sqA) * 30 * 512 + j;
  const float* xuBb = XU + (size_t)(s * 160 + n0 + 4) * 30 * 512 + j;
  const float* tAb = times + ((size_t)(bb * 8 + s) * 5 + sqA) * 30;
  const float* tBb = times + ((size_t)(bb * 8 + s) * 5 + 4) * 30;
  float* outA = outs + (size_t)(s * 160 + n0 + sqA) * 30 * 128 + j;
  float* outB = outs + (size_t)(s * 160 + n0 + 4) * 30 * 128 + j;

  __syncthreads();

  for (int t = 0; t < maxlen; ++t) {
    // prefetch XU for owned cells (independent of h/c; hides under phase A)
    float xuA[4], xuB[4];
#pragma unroll
    for (int g = 0; g < 4; ++g) xuA[g] = xuAb[(size_t)t * 512 + g * 128];
    if (hasB) {
#pragma unroll
      for (int g = 0; g < 4; ++g) xuB[g] = xuBb[(size_t)t * 512 + g * 128];
    }

    // ---- phase A: Wall partials ----
    float acc[5][4] = {};
#pragma unroll
    for (int kk4 = 0; kk4 < 8; ++kk4) {
      float4 h4[5];
#pragma unroll
      for (int sq = 0; sq < 5; ++sq)
        h4[sq] = *(const float4*)&hsm[sq][kg * 32 + kk4 * 4];
#pragma unroll
      for (int u = 0; u < 4; ++u) {
        const int kk = kk4 * 4 + u;
        const float w0 = wall_r[kk][0], w1 = wall_r[kk][1];
        const float w2 = wall_r[kk][2], w3 = wall_r[kk][3];
#pragma unroll
        for (int sq = 0; sq < 5; ++sq) {
          const float hv = ((const float*)&h4[sq])[u];
          acc[sq][0] += hv * w0; acc[sq][1] += hv * w1;
          acc[sq][2] += hv * w2; acc[sq][3] += hv * w3;
        }
      }
    }
    // ---- Wd partials ----
    float pd[5] = {};
#pragma unroll
    for (int kk4 = 0; kk4 < 8; ++kk4) {
      float4 c4[5];
#pragma unroll
      for (int sq = 0; sq < 5; ++sq)
        c4[sq] = *(const float4*)&csm[sq][kg * 32 + kk4 * 4];
#pragma unroll
      for (int u = 0; u < 4; ++u) {
        const int kk = kk4 * 4 + u;
        const float wd = wd_r[kk];
#pragma unroll
        for (int sq = 0; sq < 5; ++sq)
          pd[sq] += ((const float*)&c4[sq])[u] * wd;
      }
    }
    // write partials (lane-contiguous in j -> conflict-free)
#pragma unroll
    for (int g = 0; g < 4; ++g)
#pragma unroll
      for (int sq = 0; sq < 5; ++sq) red[g * 4 + kg][sq][j] = acc[sq][g];
#pragma unroll
    for (int sq = 0; sq < 5; ++sq) red[16 + kg][sq][j] = pd[sq];
    __syncthreads();

    // ---- phase B: owner threads finish cells ----
    {
      const int sq = sqA;
      if (t < len_[sq]) {
        float g4[4];
#pragma unroll
        for (int g = 0; g < 4; ++g)
          g4[g] = red[g * 4 + 0][sq][j] + red[g * 4 + 1][sq][j] +
                  red[g * 4 + 2][sq][j] + red[g * 4 + 3][sq][j] + blg[g] + xuA[g];
        float cs1 = red[16][sq][j] + red[17][sq][j] + red[18][sq][j] + red[19][sq][j] + bdj;
        cs1 = tanhf_(cs1);
        const float tt = tAb[t];
        const float f = sigf(g4[0]), ii = sigf(g4[1]);
        const float o = sigf(g4[2]), ct = sigf(g4[3]);
        const float cc = csm[sq][j];
        const float c2 = f * (cc + cs1 * (tt - 1.f)) + ii * ct;
        const float h2 = o * tanhf_(c2);
        csm[sq][j] = c2;
        hsm[sq][j] = h2;
        outA[(size_t)t * 128] = o;
        if (t == len_[sq] - 1) hn[(size_t)(s * 160 + n0 + sq) * 128 + j] = o;
      }
    }
    if (hasB) {
      const int sq = 4;
      if (t < len_[sq]) {
        float g4[4];
#pragma unroll
        for (int g = 0; g < 4; ++g)
          g4[g] = red[g * 4 + 0][sq][j] + red[g * 4 + 1][sq][j] +
                  red[g * 4 + 2][sq][j] + red[g * 4 + 3][sq][j] + blg[g] + xuB[g];
        float cs1 = red[16][sq][j] + red[17][sq][j] + red[18][sq][j] + red[19][sq][j] + bdj;
        cs1 = tanhf_(cs1);
        const float tt = tBb[t];
        const float f = sigf(g4[0]), ii = sigf(g4[1]);
        const float o = sigf(g4[2]), ct = sigf(g4[3]);
        const float cc = csm[sq][j];
        const float c2 = f * (cc + cs1 * (tt - 1.f)) + ii * ct;
        const float h2 = o * tanhf_(c2);
        csm[sq][j] = c2;
        hsm[sq][j] = h2;
        outB[(size_t)t * 128] = o;
        if (t == len_[sq] - 1) hn[(size_t)(s * 160 + n0 + sq) * 128 + j] = o;
      }
    }
    __syncthreads();
  }
}

// ---------------------------------------------------------------------------
// K3: attention 1, one block per (s, n). score_t = tanh(hn@W1+b1 + o_t@W2+b2)@V+bV,
//     masked softmax over t<len, ctx = sum_t w_t * o_t.
// ---------------------------------------------------------------------------
__global__ __launch_bounds__(128) void k3_attn1(const float* __restrict__ W1,
                                                const float* __restrict__ b1,
                                                const float* __restrict__ W2,
                                                const float* __restrict__ b2,
                                                const float* __restrict__ V,
                                                const float* __restrict__ bV,
                                                const float* __restrict__ outs,
                                                const float* __restrict__ hn,
                                                const int* __restrict__ lens,
                                                float* __restrict__ ctx) {
  const int s = blockIdx.y, n = blockIdx.x, j = threadIdx.x;
  const int b = n / 5, d = n % 5;
  const int len = lens[(b * 8 + s) * 5 + d];
  __shared__ float os[30][128];
  __shared__ float hns[128];
  __shared__ float score[30];
  __shared__ float red[2];

  hns[j] = hn[(size_t)(s * 160 + n) * 128 + j];
  const float* og = outs + (size_t)(s * 160 + n) * 30 * 128;
  for (int idx = j; idx < len * 128; idx += 128) (&os[0][0])[idx] = og[idx];
  __syncthreads();

  const float* W1s = W1 + (size_t)s * 16384;
  const float* W2s = W2 + (size_t)s * 16384;
  float u = b1[s * 128 + j] + b2[s * 128 + j];
  for (int k = 0; k < 128; ++k) u += hns[k] * W1s[k * 128 + j];
  const float Vj = V[s * 128 + j];
  const int lane = j & 63, wid = j >> 6;

  for (int t = 0; t < len; ++t) {
    float a = u;
    for (int k = 0; k < 128; ++k) a += os[t][k] * W2s[k * 128 + j];
    float p = tanhf_(a) * Vj;
#pragma unroll
    for (int off = 32; off; off >>= 1) p += __shfl_down(p, off);
    if (lane == 0) red[wid] = p;
    __syncthreads();
    if (j == 0) score[t] = red[0] + red[1] + bV[s];
    __syncthreads();
  }

  float m = -1e30f;
  for (int t = 0; t < len; ++t) m = fmaxf(m, score[t]);
  float sum = 0.f;
  for (int t = 0; t < len; ++t) sum += __expf(score[t] - m);
  float cx = 0.f;
  for (int t = 0; t < len; ++t) cx += __expf(score[t] - m) * os[t][j];
  ctx[(size_t)(s * 160 + n) * 128 + j] = cx / sum;
}

// ---------------------------------------------------------------------------
// K4: standard LSTM over D=5. split order i,f,g,o (tanh on g). 1 block/(s,b).
// ---------------------------------------------------------------------------
__global__ __launch_bounds__(128) void k4_lstm2(const float* __restrict__ Wih,
                                                const float* __restrict__ bih,
                                                const float* __restrict__ Whh,
                                                const float* __restrict__ bhh,
                                                const float* __restrict__ ctx,
                                                float* __restrict__ hsout,
                                                float* __restrict__ hlast) {
  const int s = blockIdx.y, b = blockIdx.x, j = threadIdx.x;
  __shared__ float hsm[128], xt[128];
  hsm[j] = 0.f;
  float c = 0.f;
  const float* Wis = Wih + (size_t)s * 65536;
  const float* Whs = Whh + (size_t)s * 65536;
  const float bi_ = bih[s * 512 + j] + bhh[s * 512 + j];
  const float bf_ = bih[s * 512 + 128 + j] + bhh[s * 512 + 128 + j];
  const float bg_ = bih[s * 512 + 256 + j] + bhh[s * 512 + 256 + j];
  const float bo_ = bih[s * 512 + 384 + j] + bhh[s * 512 + 384 + j];

  for (int d = 0; d < 5; ++d) {
    xt[j] = ctx[(size_t)(s * 160 + b * 5 + d) * 128 + j];
    __syncthreads();
    float gi = bi_, gf = bf_, gg = bg_, go = bo_;
    for (int k = 0; k < 128; ++k) {
      const float xk = xt[k], hk = hsm[k];
      gi += xk * Wis[k * 512 + j] + hk * Whs[k * 512 + j];
      gf += xk * Wis[k * 512 + 128 + j] + hk * Whs[k * 512 + 128 + j];
      gg += xk * Wis[k * 512 + 256 + j] + hk * Whs[k * 512 + 256 + j];
      go += xk * Wis[k * 512 + 384 + j] + hk * Whs[k * 512 + 384 + j];
    }
    const float c2 = sigf(gf) * c + sigf(gi) * tanhf_(gg);
    const float h2 = sigf(go) * tanhf_(c2);
    c = c2;
    __syncthreads();
    hsm[j] = h2;
    hsout[((size_t)(s * 32 + b) * 5 + d) * 128 + j] = h2;
    if (d == 4) hlast[(size_t)(s * 32 + b) * 128 + j] = h2;
    __syncthreads();
  }
}

// ---------------------------------------------------------------------------
// K5: attention 2 (no mask, D=5) + y = relu(ctx2@x1W+x1b)@x2W+x2b. 1 block/(s,b).
// ---------------------------------------------------------------------------
__global__ __launch_bounds__(128) void k5_attn2(const float* __restrict__ W1,
                                                const float* __restrict__ b1,
                                                const float* __restrict__ W2,
                                                const float* __restrict__ b2,
                                                const float* __restrict__ V,
                                                const float* __restrict__ bV,
                                                const float* __restrict__ x1W,
                                                const float* __restrict__ x1b,
                                                const float* __restrict__ x2W,
                                                const float* __restrict__ x2b,
                                                const float* __restrict__ hs,
                                                const float* __restrict__ hlast,
                                                float* __restrict__ y) {
  const int s = blockIdx.y, b = blockIdx.x, j = threadIdx.x;
  __shared__ float hl[128], hsm[5][128], t1[128], cs2[128], sc[5], red[2];
  hl[j] = hlast[(size_t)(s * 32 + b) * 128 + j];
  const float* hsrc = hs + (size_t)(s * 32 + b) * 640;
  for (int idx = j; idx < 640; idx += 128) (&hsm[0][0])[idx] = hsrc[idx];
  __syncthreads();

  const float* W1s = W1 + (size_t)s * 16384;
  const float* W2s = W2 + (size_t)s * 16384;
  float u = b1[s * 128 + j] + b2[s * 128 + j];
  for (int k = 0; k < 128; ++k) u += hl[k] * W1s[k * 128 + j];
  const float Vj = V[s * 128 + j];
  const int lane = j & 63, wid = j >> 6;

  for (int d = 0; d < 5; ++d) {
    float a = u;
    for (int k = 0; k < 128; ++k) a += hsm[d][k] * W2s[k * 128 + j];
    float p = tanhf_(a) * Vj;
#pragma unroll
    for (int off = 32; off; off >>= 1) p += __shfl_down(p, off);
    if (lane == 0) red[wid] = p;
    __syncthreads();
    if (j == 0) sc[d] = red[0] + red[1] + bV[s];
    __syncthreads();
  }

  float m = -1e30f;
  for (int d = 0; d < 5; ++d) m = fmaxf(m, sc[d]);
  float sum = 0.f;
  for (int d = 0; d < 5; ++d) sum += __expf(sc[d] - m);
  float cx = 0.f;
  for (int d = 0; d < 5; ++d) cx += __expf(sc[d] - m) * hsm[d][j];
  cs2[j] = cx / sum;
  __syncthreads();

  float a = x1b[s * 128 + j];
  for (int k = 0; k < 128; ++k) a += cs2[k] * x1W[(size_t)s * 16384 + k * 128 + j];
  t1[j] = fmaxf(a, 0.f);
  __syncthreads();

  if (j < 64) {
    float yy = x2b[s * 64 + j];
    for (int k = 0; k < 128; ++k) yy += t1[k] * x2W[(size_t)(s * 128 + k) * 64 + j];
    y[(size_t)(s * 32 + b) * 64 + j] = yy;
  }
}

// ---------------------------------------------------------------------------
// K6: xs = relu(stock@h1W+h1b)@h2W+h2b; full=[xs, text]; out = tanh(full@hcW+hcb)
// ---------------------------------------------------------------------------
__global__ __launch_bounds__(256) void k6_final(const float* __restrict__ stock,
                                                const float* __restrict__ h1W,
                                                const float* __restrict__ h1b,
                                                const float* __restrict__ h2W,
                                                const float* __restrict__ h2b,
                                                const float* __restrict__ hcW,
                                                const float* __restrict__ hcb,
                                                const float* __restrict__ yws,
                                                float* __restrict__ out) {
  const int tid = threadIdx.x;
  __shared__ float sf[32 * 17];
  __shared__ float hid[32 * 64];
  __shared__ float xs[32 * 32];
  for (int idx = tid; idx < 544; idx += 256) sf[idx] = stock[idx];
  __syncthreads();
  for (int idx = tid; idx < 2048; idx += 256) {
    const int b = idx >> 6, k = idx & 63;
    float a = h1b[k];
    for (int q = 0; q < 17; ++q) a += sf[b * 17 + q] * h1W[q * 64 + k];
    hid[idx] = fmaxf(a, 0.f);
  }
  __syncthreads();
  for (int idx = tid; idx < 1024; idx += 256) {
    const int b = idx >> 5, mm = idx & 31;
    float a = h2b[mm];
    for (int k = 0; k < 64; ++k) a += hid[b * 64 + k] * h2W[k * 32 + mm];
    xs[idx] = a;
  }
  __syncthreads();
  {
    const int b = tid >> 3, o = tid & 7;
    float a = hcb[o];
    for (int c = 0; c < 32; ++c) a += xs[b * 32 + c] * hcW[c * 8 + o];
    for (int c = 32; c < 544; ++c) {
      const int ss = (c - 32) >> 6, k = (c - 32) & 63;
      a += yws[((size_t)ss * 32 + b) * 64 + k] * hcW[c * 8 + o];
    }
    out[tid] = tanhf_(a);
  }
}

// ---------------------------------------------------------------------------
extern "C" void kernel_launch(void* const* d_in, const int* in_sizes, int n_in,
                              void* d_out, int out_size, void* d_ws, size_t ws_size,
                              hipStream_t stream) {
  (void)in_sizes; (void)n_in; (void)out_size; (void)ws_size;
  const float* stock = (const float*)d_in[0];
  const float* sent  = (const float*)d_in[1];
  const float* times = (const float*)d_in[2];
  const int*   lens  = (const int*)d_in[3];
  const float* tlWall = (const float*)d_in[4];
  const float* tlball = (const float*)d_in[5];
  const float* tlUall = (const float*)d_in[6];
  const float* tlbU   = (const float*)d_in[7];
  const float* tlWd   = (const float*)d_in[8];
  const float* tlbd   = (const float*)d_in[9];
  const float* a1W1 = (const float*)d_in[10];
  const float* a1b1 = (const float*)d_in[11];
  const float* a1W2 = (const float*)d_in[12];
  const float* a1b2 = (const float*)d_in[13];
  const float* a1V  = (const float*)d_in[14];
  const float* a1bV = (const float*)d_in[15];
  const float* l2Wih = (const float*)d_in[16];
  const float* l2bih = (const float*)d_in[17];
  const float* l2Whh = (const float*)d_in[18];
  const float* l2bhh = (const float*)d_in[19];
  const float* a2W1 = (const float*)d_in[20];
  const float* a2b1 = (const float*)d_in[21];
  const float* a2W2 = (const float*)d_in[22];
  const float* a2b2 = (const float*)d_in[23];
  const float* a2V  = (const float*)d_in[24];
  const float* a2bV = (const float*)d_in[25];
  const float* x1W  = (const float*)d_in[26];
  const float* x1b  = (const float*)d_in[27];
  const float* x2W  = (const float*)d_in[28];
  const float* x2b  = (const float*)d_in[29];
  const float* h1W  = (const float*)d_in[30];
  const float* h1b  = (const float*)d_in[31];
  const float* h2W  = (const float*)d_in[32];
  const float* h2b  = (const float*)d_in[33];
  const float* hcW  = (const float*)d_in[34];
  const float* hcb  = (const float*)d_in[35];

  float* ws = (float*)d_ws;
  float* XU    = ws;               // 8*160*30*512   = 19,660,800
  float* outs  = XU + 19660800;    // 8*160*30*128   =  4,915,200
  float* hnb   = outs + 4915200;   // 8*160*128      =    163,840
  float* ctx   = hnb + 163840;     // 8*160*128      =    163,840
  float* hsb   = ctx + 163840;     // 8*32*5*128     =    163,840
  float* hlast = hsb + 163840;     // 8*32*128       =     32,768
  float* yb    = hlast + 32768;    // 8*32*64        =     16,384

  k1_xu<<<dim3(75, 8, 8), 256, 0, stream>>>(sent, tlUall, tlbU, XU);
  k2_tlstm<<<dim3(32, 8), 512, 0, stream>>>(tlWall, tlball, tlWd, tlbd, XU, times, lens, outs, hnb);
  k3_attn1<<<dim3(160, 8), 128, 0, stream>>>(a1W1, a1b1, a1W2, a1b2, a1V, a1bV, outs, hnb, lens, ctx);
  k4_lstm2<<<dim3(32, 8), 128, 0, stream>>>(l2Wih, l2bih, l2Whh, l2bhh, ctx, hsb, hlast);
  k5_attn2<<<dim3(32, 8), 128, 0, stream>>>(a2W1, a2b1, a2W2, a2b2, a2V, a2bV, x1W, x1b, x2W, x2b, hsb, hlast, yb);
  k6_final<<<1, 256, 0, stream>>>(stock, h1W, h1b, h2W, h2b, hcW, hcb, yb, (float*)d_out);
}

// Round 3
// 396.554 us; speedup vs baseline: 3.3250x; 1.9727x over previous
//
#include <hip/hip_runtime.h>
#include <cstddef>

// Problem constants: S=8, B=32, D=5, T=30, E=768, H=128, 4H=512.

typedef __attribute__((ext_vector_type(8))) _Float16 f16x8;
typedef __attribute__((ext_vector_type(4))) float f32x4;

__device__ __forceinline__ float sigf(float x) { return 1.0f / (1.0f + __expf(-x)); }
__device__ __forceinline__ float tanhf_(float x) { return 1.0f - 2.0f / (__expf(2.0f * x) + 1.0f); }

// ---------------------------------------------------------------------------
// K0: split+transpose U: Uh[s][n][k] = f16(U[s][k][n]); Ul[s][n][k] =
//     f16((U - Uh) * 2048)  (pre-scaled so the residual is fp16-normal).
// ---------------------------------------------------------------------------
__global__ __launch_bounds__(128) void k0_usplit(const float* __restrict__ U,
                                                 _Float16* __restrict__ Uh,
                                                 _Float16* __restrict__ Ul) {
  const int s = blockIdx.y;
  const int n = blockIdx.x;
  const int tid = threadIdx.x;
  const float* Us = U + (size_t)s * 768 * 512 + n;
  _Float16* uh = Uh + ((size_t)s * 512 + n) * 768;
  _Float16* ul = Ul + ((size_t)s * 512 + n) * 768;
  for (int k = tid; k < 768; k += 128) {
    const float u = Us[(size_t)k * 512];
    const _Float16 h = (_Float16)u;
    uh[k] = h;
    ul[k] = (_Float16)((u - (float)h) * 2048.0f);
  }
}

// ---------------------------------------------------------------------------
// K1 v2: XU = x @ U + bU via MFMA f32_16x16x32_f16, 2-product fp16 split.
//   Tile M128 x N128, K=768 in 24 steps of 32. 256 thr = 4 waves (2x2 of 64x64).
//   acc += mfma(a_hi, U_hi) + mfma(a_hi * 2^-11, U_lo * 2^11).
//   A reg-staged from fp32 sentence_feat with inline cvt; B copied f16.
//   LDS double-buffered; one barrier per K-step (stage next || compute cur).
// ---------------------------------------------------------------------------
__global__ __launch_bounds__(256, 2) void k1_xu(const float* __restrict__ sent,
                                                const _Float16* __restrict__ Uh,
                                                const _Float16* __restrict__ Ul,
                                                const float* __restrict__ bU,
                                                float* __restrict__ XU) {
  const int s = blockIdx.z;
  const int nt = blockIdx.x & 3;
  const int mt = blockIdx.x >> 2;
  const int tid = threadIdx.x;
  const int lane = tid & 63, wid = tid >> 6;
  const int wm = wid >> 1, wn = wid & 1;

  __shared__ _Float16 Al[2][128 * 32];
  __shared__ _Float16 Bh[2][128 * 32];
  __shared__ _Float16 Bl[2][128 * 32];

  // staging: thread owns 16B chunks tid and tid+256 of each 8KB buffer:
  //   chunk c -> row c>>2 (32-half rows), half-offset (c&3)*8
  const int ar1 = tid >> 2;          // rows ar1 and ar1+64
  const int afk = (tid & 3) * 8;     // element offset within the 32-wide k slice

  const float* asrc1;
  const float* asrc2;
  {
    int gr = mt * 128 + ar1; if (gr > 4799) gr = 4799;
    const int nn = gr / 30, tt = gr % 30, ab = nn / 5, ad = nn % 5;
    asrc1 = sent + (size_t)((((ab * 8 + s) * 5 + ad) * 30) + tt) * 768 + afk;
  }
  {
    int gr = mt * 128 + ar1 + 64; if (gr > 4799) gr = 4799;
    const int nn = gr / 30, tt = gr % 30, ab = nn / 5, ad = nn % 5;
    asrc2 = sent + (size_t)((((ab * 8 + s) * 5 + ad) * 30) + tt) * 768 + afk;
  }
  const _Float16* UhS = Uh + (size_t)s * 512 * 768;
  const _Float16* UlS = Ul + (size_t)s * 512 * 768;
  const _Float16* bh1 = UhS + (size_t)(nt * 128 + ar1) * 768 + afk;
  const _Float16* bh2 = UhS + (size_t)(nt * 128 + ar1 + 64) * 768 + afk;
  const _Float16* bl1 = UlS + (size_t)(nt * 128 + ar1) * 768 + afk;
  const _Float16* bl2 = UlS + (size_t)(nt * 128 + ar1 + 64) * 768 + afk;

  const _Float16 hsc = (_Float16)0.00048828125f;  // 2^-11
  const f16x8 sc8 = {hsc, hsc, hsc, hsc, hsc, hsc, hsc, hsc};

  f32x4 acc[4][4];
#pragma unroll
  for (int i = 0; i < 4; ++i)
#pragma unroll
    for (int j = 0; j < 4; ++j) acc[i][j] = (f32x4){0.f, 0.f, 0.f, 0.f};

  // ---- prologue: stage ks=0 into buf 0 ----
  {
    const float4 a1a = *(const float4*)(asrc1);
    const float4 a1b = *(const float4*)(asrc1 + 4);
    const float4 a2a = *(const float4*)(asrc2);
    const float4 a2b = *(const float4*)(asrc2 + 4);
    const f16x8 vh1 = *(const f16x8*)(bh1);
    const f16x8 vh2 = *(const f16x8*)(bh2);
    const f16x8 vl1 = *(const f16x8*)(bl1);
    const f16x8 vl2 = *(const f16x8*)(bl2);
    f16x8 h1, h2;
    h1[0]=(_Float16)a1a.x; h1[1]=(_Float16)a1a.y; h1[2]=(_Float16)a1a.z; h1[3]=(_Float16)a1a.w;
    h1[4]=(_Float16)a1b.x; h1[5]=(_Float16)a1b.y; h1[6]=(_Float16)a1b.z; h1[7]=(_Float16)a1b.w;
    h2[0]=(_Float16)a2a.x; h2[1]=(_Float16)a2a.y; h2[2]=(_Float16)a2a.z; h2[3]=(_Float16)a2a.w;
    h2[4]=(_Float16)a2b.x; h2[5]=(_Float16)a2b.y; h2[6]=(_Float16)a2b.z; h2[7]=(_Float16)a2b.w;
    *(f16x8*)&Al[0][tid * 8] = h1;
    *(f16x8*)&Al[0][tid * 8 + 2048] = h2;
    *(f16x8*)&Bh[0][tid * 8] = vh1;
    *(f16x8*)&Bh[0][tid * 8 + 2048] = vh2;
    *(f16x8*)&Bl[0][tid * 8] = vl1;
    *(f16x8*)&Bl[0][tid * 8 + 2048] = vl2;
  }
  __syncthreads();

  const int khalf = (lane >> 4) * 8;
  const int l15 = lane & 15;

  int cur = 0;
  for (int ks = 0; ks < 24; ++ks) {
    const int nxt = cur ^ 1;
    const bool more = (ks < 23);
    float4 a1a, a1b, a2a, a2b;
    f16x8 vh1, vh2, vl1, vl2;
    if (more) {
      const int ko = (ks + 1) * 32;
      a1a = *(const float4*)(asrc1 + ko);
      a1b = *(const float4*)(asrc1 + ko + 4);
      a2a = *(const float4*)(asrc2 + ko);
      a2b = *(const float4*)(asrc2 + ko + 4);
      vh1 = *(const f16x8*)(bh1 + ko);
      vh2 = *(const f16x8*)(bh2 + ko);
      vl1 = *(const f16x8*)(bl1 + ko);
      vl2 = *(const f16x8*)(bl2 + ko);
    }

    // ---- compute on cur ----
    {
      const _Float16* Ab = &Al[cur][0];
      const _Float16* Bhb = &Bh[cur][0];
      const _Float16* Blb = &Bl[cur][0];
      f16x8 af[4], asf[4], bhf[4], blf[4];
#pragma unroll
      for (int fm = 0; fm < 4; ++fm) {
        const int row = wm * 64 + fm * 16 + l15;
        af[fm] = *(const f16x8*)&Ab[row * 32 + khalf];
        asf[fm] = af[fm] * sc8;
      }
#pragma unroll
      for (int fn = 0; fn < 4; ++fn) {
        const int row = wn * 64 + fn * 16 + l15;
        bhf[fn] = *(const f16x8*)&Bhb[row * 32 + khalf];
        blf[fn] = *(const f16x8*)&Blb[row * 32 + khalf];
      }
#pragma unroll
      for (int fm = 0; fm < 4; ++fm)
#pragma unroll
        for (int fn = 0; fn < 4; ++fn) {
          acc[fm][fn] = __builtin_amdgcn_mfma_f32_16x16x32_f16(af[fm], bhf[fn], acc[fm][fn], 0, 0, 0);
          acc[fm][fn] = __builtin_amdgcn_mfma_f32_16x16x32_f16(asf[fm], blf[fn], acc[fm][fn], 0, 0, 0);
        }
    }

    if (more) {
      f16x8 h1, h2;
      h1[0]=(_Float16)a1a.x; h1[1]=(_Float16)a1a.y; h1[2]=(_Float16)a1a.z; h1[3]=(_Float16)a1a.w;
      h1[4]=(_Float16)a1b.x; h1[5]=(_Float16)a1b.y; h1[6]=(_Float16)a1b.z; h1[7]=(_Float16)a1b.w;
      h2[0]=(_Float16)a2a.x; h2[1]=(_Float16)a2a.y; h2[2]=(_Float16)a2a.z; h2[3]=(_Float16)a2a.w;
      h2[4]=(_Float16)a2b.x; h2[5]=(_Float16)a2b.y; h2[6]=(_Float16)a2b.z; h2[7]=(_Float16)a2b.w;
      *(f16x8*)&Al[nxt][tid * 8] = h1;
      *(f16x8*)&Al[nxt][tid * 8 + 2048] = h2;
      *(f16x8*)&Bh[nxt][tid * 8] = vh1;
      *(f16x8*)&Bh[nxt][tid * 8 + 2048] = vh2;
      *(f16x8*)&Bl[nxt][tid * 8] = vl1;
      *(f16x8*)&Bl[nxt][tid * 8 + 2048] = vl2;
    }
    __syncthreads();
    cur = nxt;
  }

  // ---- epilogue: D[row=(l>>4)*4+r][col=l&15] per 16x16 frag; add bias ----
  const int lq = lane >> 4;
  const int colbase = nt * 128 + wn * 64;
  const int rowbase = mt * 128 + wm * 64;
  float* XUs = XU + (size_t)s * 4800 * 512;
#pragma unroll
  for (int fn = 0; fn < 4; ++fn) {
    const int col = colbase + fn * 16 + l15;
    const float bias = bU[s * 512 + col];
#pragma unroll
    for (int fm = 0; fm < 4; ++fm) {
      const int r0 = rowbase + fm * 16 + lq * 4;
#pragma unroll
      for (int r = 0; r < 4; ++r) {
        const int row = r0 + r;
        if (row < 4800) XUs[(size_t)row * 512 + col] = acc[fm][fn][r] + bias;
      }
    }
  }
}

// ---------------------------------------------------------------------------
// K2: weight-stationary time-LSTM recurrence (unchanged from round 2).
// ---------------------------------------------------------------------------
__global__ __launch_bounds__(512, 2) void k2_tlstm(const float* __restrict__ Wall,
                                                   const float* __restrict__ ball,
                                                   const float* __restrict__ Wd,
                                                   const float* __restrict__ bd,
                                                   const float* __restrict__ XU,
                                                   const float* __restrict__ times,
                                                   const int* __restrict__ lens,
                                                   float* __restrict__ outs,
                                                   float* __restrict__ hn) {
  const int s = blockIdx.y;
  const int bb = blockIdx.x;
  const int n0 = bb * 5;
  const int tid = threadIdx.x;
  const int j = tid & 127;
  const int kg = tid >> 7;

  __shared__ float hsm[5][128];
  __shared__ float csm[5][128];
  __shared__ float red[20][5][128];

  for (int idx = tid; idx < 640; idx += 512) {
    (&hsm[0][0])[idx] = 0.f;
    (&csm[0][0])[idx] = 0.f;
  }

  int len_[5];
  int maxlen = 0;
#pragma unroll
  for (int d = 0; d < 5; ++d) {
    len_[d] = lens[(bb * 8 + s) * 5 + d];
    maxlen = max(maxlen, len_[d]);
  }

  float wall_r[32][4];
  float wd_r[32];
  {
    const float* Wb = Wall + (size_t)s * 65536 + (size_t)(kg * 32) * 512 + j;
    const float* Db = Wd + (size_t)s * 16384 + (size_t)(kg * 32) * 128 + j;
#pragma unroll
    for (int kk = 0; kk < 32; ++kk) {
#pragma unroll
      for (int g = 0; g < 4; ++g) wall_r[kk][g] = Wb[kk * 512 + g * 128];
      wd_r[kk] = Db[kk * 128];
    }
  }

  const float bdj = bd[s * 128 + j];
  float blg[4];
#pragma unroll
  for (int g = 0; g < 4; ++g) blg[g] = ball[s * 512 + g * 128 + j];

  const int sqA = kg;
  const bool hasB = (kg == 0);
  const float* xuAb = XU + (size_t)(s * 160 + n0 + sqA) * 30 * 512 + j;
  const float* xuBb = XU + (size_t)(s * 160 + n0 + 4) * 30 * 512 + j;
  const float* tAb = times + ((size_t)(bb * 8 + s) * 5 + sqA) * 30;
  const float* tBb = times + ((size_t)(bb * 8 + s) * 5 + 4) * 30;
  float* outA = outs + (size_t)(s * 160 + n0 + sqA) * 30 * 128 + j;
  float* outB = outs + (size_t)(s * 160 + n0 + 4) * 30 * 128 + j;

  __syncthreads();

  for (int t = 0; t < maxlen; ++t) {
    float xuA[4], xuB[4];
#pragma unroll
    for (int g = 0; g < 4; ++g) xuA[g] = xuAb[(size_t)t * 512 + g * 128];
    if (hasB) {
#pragma unroll
      for (int g = 0; g < 4; ++g) xuB[g] = xuBb[(size_t)t * 512 + g * 128];
    }

    float acc[5][4] = {};
#pragma unroll
    for (int kk4 = 0; kk4 < 8; ++kk4) {
      float4 h4[5];
#pragma unroll
      for (int sq = 0; sq < 5; ++sq)
        h4[sq] = *(const float4*)&hsm[sq][kg * 32 + kk4 * 4];
#pragma unroll
      for (int u = 0; u < 4; ++u) {
        const int kk = kk4 * 4 + u;
        const float w0 = wall_r[kk][0], w1 = wall_r[kk][1];
        const float w2 = wall_r[kk][2], w3 = wall_r[kk][3];
#pragma unroll
        for (int sq = 0; sq < 5; ++sq) {
          const float hv = ((const float*)&h4[sq])[u];
          acc[sq][0] += hv * w0; acc[sq][1] += hv * w1;
          acc[sq][2] += hv * w2; acc[sq][3] += hv * w3;
        }
      }
    }
    float pd[5] = {};
#pragma unroll
    for (int kk4 = 0; kk4 < 8; ++kk4) {
      float4 c4[5];
#pragma unroll
      for (int sq = 0; sq < 5; ++sq)
        c4[sq] = *(const float4*)&csm[sq][kg * 32 + kk4 * 4];
#pragma unroll
      for (int u = 0; u < 4; ++u) {
        const int kk = kk4 * 4 + u;
        const float wd = wd_r[kk];
#pragma unroll
        for (int sq = 0; sq < 5; ++sq)
          pd[sq] += ((const float*)&c4[sq])[u] * wd;
      }
    }
#pragma unroll
    for (int g = 0; g < 4; ++g)
#pragma unroll
      for (int sq = 0; sq < 5; ++sq) red[g * 4 + kg][sq][j] = acc[sq][g];
#pragma unroll
    for (int sq = 0; sq < 5; ++sq) red[16 + kg][sq][j] = pd[sq];
    __syncthreads();

    {
      const int sq = sqA;
      if (t < len_[sq]) {
        float g4[4];
#pragma unroll
        for (int g = 0; g < 4; ++g)
          g4[g] = red[g * 4 + 0][sq][j] + red[g * 4 + 1][sq][j] +
                  red[g * 4 + 2][sq][j] + red[g * 4 + 3][sq][j] + blg[g] + xuA[g];
        float cs1 = red[16][sq][j] + red[17][sq][j] + red[18][sq][j] + red[19][sq][j] + bdj;
        cs1 = tanhf_(cs1);
        const float tt = tAb[t];
        const float f = sigf(g4[0]), ii = sigf(g4[1]);
        const float o = sigf(g4[2]), ct = sigf(g4[3]);
        const float cc = csm[sq][j];
        const float c2 = f * (cc + cs1 * (tt - 1.f)) + ii * ct;
        const float h2 = o * tanhf_(c2);
        csm[sq][j] = c2;
        hsm[sq][j] = h2;
        outA[(size_t)t * 128] = o;
        if (t == len_[sq] - 1) hn[(size_t)(s * 160 + n0 + sq) * 128 + j] = o;
      }
    }
    if (hasB) {
      const int sq = 4;
      if (t < len_[sq]) {
        float g4[4];
#pragma unroll
        for (int g = 0; g < 4; ++g)
          g4[g] = red[g * 4 + 0][sq][j] + red[g * 4 + 1][sq][j] +
                  red[g * 4 + 2][sq][j] + red[g * 4 + 3][sq][j] + blg[g] + xuB[g];
        float cs1 = red[16][sq][j] + red[17][sq][j] + red[18][sq][j] + red[19][sq][j] + bdj;
        cs1 = tanhf_(cs1);
        const float tt = tBb[t];
        const float f = sigf(g4[0]), ii = sigf(g4[1]);
        const float o = sigf(g4[2]), ct = sigf(g4[3]);
        const float cc = csm[sq][j];
        const float c2 = f * (cc + cs1 * (tt - 1.f)) + ii * ct;
        const float h2 = o * tanhf_(c2);
        csm[sq][j] = c2;
        hsm[sq][j] = h2;
        outB[(size_t)t * 128] = o;
        if (t == len_[sq] - 1) hn[(size_t)(s * 160 + n0 + sq) * 128 + j] = o;
      }
    }
    __syncthreads();
  }
}

// ---------------------------------------------------------------------------
// K3 v2: attention 1, per-wave t-scores (no per-t block barriers).
// ---------------------------------------------------------------------------
__global__ __launch_bounds__(128) void k3_attn1(const float* __restrict__ W1,
                                                const float* __restrict__ b1,
                                                const float* __restrict__ W2,
                                                const float* __restrict__ b2,
                                                const float* __restrict__ V,
                                                const float* __restrict__ bV,
                                                const float* __restrict__ outs,
                                                const float* __restrict__ hn,
                                                const int* __restrict__ lens,
                                                float* __restrict__ ctx) {
  const int s = blockIdx.y, n = blockIdx.x, j = threadIdx.x;
  const int b = n / 5, d = n % 5;
  const int len = lens[(b * 8 + s) * 5 + d];
  __shared__ float os[30][128];
  __shared__ float hns[128];
  __shared__ float u_sh[128];
  __shared__ float score[30];

  hns[j] = hn[(size_t)(s * 160 + n) * 128 + j];
  const float* og = outs + (size_t)(s * 160 + n) * 30 * 128;
  for (int idx = j; idx < len * 128; idx += 128) (&os[0][0])[idx] = og[idx];
  __syncthreads();

  const float* W1s = W1 + (size_t)s * 16384;
  float u = b1[s * 128 + j] + b2[s * 128 + j];
  for (int k = 0; k < 128; ++k) u += hns[k] * W1s[k * 128 + j];
  u_sh[j] = u;
  __syncthreads();

  const float* W2s = W2 + (size_t)s * 16384;
  const float bVs = bV[s];
  const int lane = j & 63, wid = j >> 6;
  const float V0 = V[s * 128 + lane], V1 = V[s * 128 + 64 + lane];

  for (int t = wid; t < len; t += 2) {
    float a0 = u_sh[lane], a1 = u_sh[64 + lane];
    for (int k = 0; k < 128; ++k) {
      const float ok = os[t][k];
      a0 += ok * W2s[k * 128 + lane];
      a1 += ok * W2s[k * 128 + 64 + lane];
    }
    float p = tanhf_(a0) * V0 + tanhf_(a1) * V1;
#pragma unroll
    for (int off = 32; off; off >>= 1) p += __shfl_down(p, off);
    if (lane == 0) score[t] = p + bVs;
  }
  __syncthreads();

  float m = -1e30f;
  for (int t = 0; t < len; ++t) m = fmaxf(m, score[t]);
  float sum = 0.f;
  for (int t = 0; t < len; ++t) sum += __expf(score[t] - m);
  float cx = 0.f;
  for (int t = 0; t < len; ++t) cx += __expf(score[t] - m) * os[t][j];
  ctx[(size_t)(s * 160 + n) * 128 + j] = cx / sum;
}

// ---------------------------------------------------------------------------
// K4 v2: LSTM over D=5, 512 threads (one per gate-unit), Whh reg-stationary.
//   Gate split order i,f,g,o (tanh on g).
// ---------------------------------------------------------------------------
__global__ __launch_bounds__(512) void k4_lstm2(const float* __restrict__ Wih,
                                                const float* __restrict__ bih,
                                                const float* __restrict__ Whh,
                                                const float* __restrict__ bhh,
                                                const float* __restrict__ ctx,
                                                float* __restrict__ hsout,
                                                float* __restrict__ hlast) {
  const int s = blockIdx.y, b = blockIdx.x;
  const int gj = threadIdx.x;  // 0..511
  __shared__ float xs[5][128];
  __shared__ float hsm[128];
  __shared__ float gsh[512];

  for (int idx = gj; idx < 640; idx += 512)
    (&xs[0][0])[idx] = ctx[(size_t)(s * 160 + b * 5) * 128 + idx];
  if (gj < 128) hsm[gj] = 0.f;
  __syncthreads();

  const float* Wis = Wih + (size_t)s * 65536;
  const float* Whs = Whh + (size_t)s * 65536;
  const float bias = bih[s * 512 + gj] + bhh[s * 512 + gj];
  float xw[5] = {bias, bias, bias, bias, bias};
  float whh[128];
#pragma unroll
  for (int k = 0; k < 128; ++k) {
    const float wi = Wis[k * 512 + gj];
    whh[k] = Whs[k * 512 + gj];
#pragma unroll
    for (int dd = 0; dd < 5; ++dd) xw[dd] += xs[dd][k] * wi;
  }

  float c = 0.f;
  for (int dd = 0; dd < 5; ++dd) {
    float g = xw[dd];
#pragma unroll
    for (int k = 0; k < 128; ++k) g += hsm[k] * whh[k];
    gsh[gj] = g;
    __syncthreads();
    if (gj < 128) {
      const int j = gj;
      const float c2 = sigf(gsh[128 + j]) * c + sigf(gsh[j]) * tanhf_(gsh[256 + j]);
      const float h2 = sigf(gsh[384 + j]) * tanhf_(c2);
      c = c2;
      hsm[j] = h2;
      hsout[((size_t)(s * 32 + b) * 5 + dd) * 128 + j] = h2;
      if (dd == 4) hlast[(size_t)(s * 32 + b) * 128 + j] = h2;
    }
    __syncthreads();
  }
}

// ---------------------------------------------------------------------------
// K5: attention 2 (no mask, D=5) + y = relu(ctx2@x1W+x1b)@x2W+x2b. 1 block/(s,b).
// ---------------------------------------------------------------------------
__global__ __launch_bounds__(128) void k5_attn2(const float* __restrict__ W1,
                                                const float* __restrict__ b1,
                                                const float* __restrict__ W2,
                                                const float* __restrict__ b2,
                                                const float* __restrict__ V,
                                                const float* __restrict__ bV,
                                                const float* __restrict__ x1W,
                                                const float* __restrict__ x1b,
                                                const float* __restrict__ x2W,
                                                const float* __restrict__ x2b,
                                                const float* __restrict__ hs,
                                                const float* __restrict__ hlast,
                                                float* __restrict__ y) {
  const int s = blockIdx.y, b = blockIdx.x, j = threadIdx.x;
  __shared__ float hl[128], hsm[5][128], t1[128], cs2[128], sc[5], red[2];
  hl[j] = hlast[(size_t)(s * 32 + b) * 128 + j];
  const float* hsrc = hs + (size_t)(s * 32 + b) * 640;
  for (int idx = j; idx < 640; idx += 128) (&hsm[0][0])[idx] = hsrc[idx];
  __syncthreads();

  const float* W1s = W1 + (size_t)s * 16384;
  const float* W2s = W2 + (size_t)s * 16384;
  float u = b1[s * 128 + j] + b2[s * 128 + j];
  for (int k = 0; k < 128; ++k) u += hl[k] * W1s[k * 128 + j];
  const float Vj = V[s * 128 + j];
  const int lane = j & 63, wid = j >> 6;

  for (int d = 0; d < 5; ++d) {
    float a = u;
    for (int k = 0; k < 128; ++k) a += hsm[d][k] * W2s[k * 128 + j];
    float p = tanhf_(a) * Vj;
#pragma unroll
    for (int off = 32; off; off >>= 1) p += __shfl_down(p, off);
    if (lane == 0) red[wid] = p;
    __syncthreads();
    if (j == 0) sc[d] = red[0] + red[1] + bV[s];
    __syncthreads();
  }

  float m = -1e30f;
  for (int d = 0; d < 5; ++d) m = fmaxf(m, sc[d]);
  float sum = 0.f;
  for (int d = 0; d < 5; ++d) sum += __expf(sc[d] - m);
  float cx = 0.f;
  for (int d = 0; d < 5; ++d) cx += __expf(sc[d] - m) * hsm[d][j];
  cs2[j] = cx / sum;
  __syncthreads();

  float a = x1b[s * 128 + j];
  for (int k = 0; k < 128; ++k) a += cs2[k] * x1W[(size_t)s * 16384 + k * 128 + j];
  t1[j] = fmaxf(a, 0.f);
  __syncthreads();

  if (j < 64) {
    float yy = x2b[s * 64 + j];
    for (int k = 0; k < 128; ++k) yy += t1[k] * x2W[(size_t)(s * 128 + k) * 64 + j];
    y[(size_t)(s * 32 + b) * 64 + j] = yy;
  }
}

// ---------------------------------------------------------------------------
// K6: xs = relu(stock@h1W+h1b)@h2W+h2b; full=[xs, text]; out = tanh(full@hcW+hcb)
// ---------------------------------------------------------------------------
__global__ __launch_bounds__(256) void k6_final(const float* __restrict__ stock,
                                                const float* __restrict__ h1W,
                                                const float* __restrict__ h1b,
                                                const float* __restrict__ h2W,
                                                const float* __restrict__ h2b,
                                                const float* __restrict__ hcW,
                                                const float* __restrict__ hcb,
                                                const float* __restrict__ yws,
                                                float* __restrict__ out) {
  const int tid = threadIdx.x;
  __shared__ float sf[32 * 17];
  __shared__ float hid[32 * 64];
  __shared__ float xs[32 * 32];
  for (int idx = tid; idx < 544; idx += 256) sf[idx] = stock[idx];
  __syncthreads();
  for (int idx = tid; idx < 2048; idx += 256) {
    const int b = idx >> 6, k = idx & 63;
    float a = h1b[k];
    for (int q = 0; q < 17; ++q) a += sf[b * 17 + q] * h1W[q * 64 + k];
    hid[idx] = fmaxf(a, 0.f);
  }
  __syncthreads();
  for (int idx = tid; idx < 1024; idx += 256) {
    const int b = idx >> 5, mm = idx & 31;
    float a = h2b[mm];
    for (int k = 0; k < 64; ++k) a += hid[b * 64 + k] * h2W[k * 32 + mm];
    xs[idx] = a;
  }
  __syncthreads();
  {
    const int b = tid >> 3, o = tid & 7;
    float a = hcb[o];
    for (int c = 0; c < 32; ++c) a += xs[b * 32 + c] * hcW[c * 8 + o];
    for (int c = 32; c < 544; ++c) {
      const int ss = (c - 32) >> 6, k = (c - 32) & 63;
      a += yws[((size_t)ss * 32 + b) * 64 + k] * hcW[c * 8 + o];
    }
    out[tid] = tanhf_(a);
  }
}

// ---------------------------------------------------------------------------
extern "C" void kernel_launch(void* const* d_in, const int* in_sizes, int n_in,
                              void* d_out, int out_size, void* d_ws, size_t ws_size,
                              hipStream_t stream) {
  (void)in_sizes; (void)n_in; (void)out_size; (void)ws_size;
  const float* stock = (const float*)d_in[0];
  const float* sent  = (const float*)d_in[1];
  const float* times = (const float*)d_in[2];
  const int*   lens  = (const int*)d_in[3];
  const float* tlWall = (const float*)d_in[4];
  const float* tlball = (const float*)d_in[5];
  const float* tlUall = (const float*)d_in[6];
  const float* tlbU   = (const float*)d_in[7];
  const float* tlWd   = (const float*)d_in[8];
  const float* tlbd   = (const float*)d_in[9];
  const float* a1W1 = (const float*)d_in[10];
  const float* a1b1 = (const float*)d_in[11];
  const float* a1W2 = (const float*)d_in[12];
  const float* a1b2 = (const float*)d_in[13];
  const float* a1V  = (const float*)d_in[14];
  const float* a1bV = (const float*)d_in[15];
  const float* l2Wih = (const float*)d_in[16];
  const float* l2bih = (const float*)d_in[17];
  const float* l2Whh = (const float*)d_in[18];
  const float* l2bhh = (const float*)d_in[19];
  const float* a2W1 = (const float*)d_in[20];
  const float* a2b1 = (const float*)d_in[21];
  const float* a2W2 = (const float*)d_in[22];
  const float* a2b2 = (const float*)d_in[23];
  const float* a2V  = (const float*)d_in[24];
  const float* a2bV = (const float*)d_in[25];
  const float* x1W  = (const float*)d_in[26];
  const float* x1b  = (const float*)d_in[27];
  const float* x2W  = (const float*)d_in[28];
  const float* x2b  = (const float*)d_in[29];
  const float* h1W  = (const float*)d_in[30];
  const float* h1b  = (const float*)d_in[31];
  const float* h2W  = (const float*)d_in[32];
  const float* h2b  = (const float*)d_in[33];
  const float* hcW  = (const float*)d_in[34];
  const float* hcb  = (const float*)d_in[35];

  float* ws = (float*)d_ws;
  float* XU    = ws;               // 8*160*30*512   = 19,660,800
  float* outs  = XU + 19660800;    // 8*160*30*128   =  4,915,200
  float* hnb   = outs + 4915200;   // 8*160*128      =    163,840
  float* ctx   = hnb + 163840;     // 8*160*128      =    163,840
  float* hsb   = ctx + 163840;     // 8*32*5*128     =    163,840
  float* hlast = hsb + 163840;     // 8*32*128       =     32,768
  float* yb    = hlast + 32768;    // 8*32*64        =     16,384
  _Float16* Uhw = (_Float16*)(yb + 16384);   // 8*512*768 halfs
  _Float16* Ulw = Uhw + 8 * 512 * 768;       // 8*512*768 halfs

  k0_usplit<<<dim3(512, 8), 128, 0, stream>>>(tlUall, Uhw, Ulw);
  k1_xu<<<dim3(152, 1, 8), 256, 0, stream>>>(sent, Uhw, Ulw, tlbU, XU);
  k2_tlstm<<<dim3(32, 8), 512, 0, stream>>>(tlWall, tlball, tlWd, tlbd, XU, times, lens, outs, hnb);
  k3_attn1<<<dim3(160, 8), 128, 0, stream>>>(a1W1, a1b1, a1W2, a1b2, a1V, a1bV, outs, hnb, lens, ctx);
  k4_lstm2<<<dim3(32, 8), 512, 0, stream>>>(l2Wih, l2bih, l2Whh, l2bhh, ctx, hsb, hlast);
  k5_attn2<<<dim3(32, 8), 128, 0, stream>>>(a2W1, a2b1, a2W2, a2b2, a2V, a2bV, x1W, x1b, x2W, x2b, hsb, hlast, yb);
  k6_final<<<1, 256, 0, stream>>>(stock, h1W, h1b, h2W, h2b, hcW, hcb, yb, (float*)d_out);
}

// Round 4
// 337.557 us; speedup vs baseline: 3.9061x; 1.1748x over previous
//
#include <hip/hip_runtime.h>
#include <cstddef>

// Problem constants: S=8, B=32, D=5, T=30, E=768, H=128, 4H=512.

typedef __attribute__((ext_vector_type(8))) _Float16 f16x8;
typedef __attribute__((ext_vector_type(2))) _Float16 f16x2;
typedef __attribute__((ext_vector_type(4))) float f32x4;

__device__ __forceinline__ float sigf(float x) { return 1.0f / (1.0f + __expf(-x)); }
__device__ __forceinline__ float tanhf_(float x) { return 1.0f - 2.0f / (__expf(2.0f * x) + 1.0f); }

// ---------------------------------------------------------------------------
// K0r: per-stock compacted row map: rows (n,t) with t < len[s,n].
//   rowmap[s][i] = n*30+t for i in [0, Ms[s]); Ms[s] = sum of lens.
// ---------------------------------------------------------------------------
__global__ __launch_bounds__(256) void k0_rowmap(const int* __restrict__ lens,
                                                 int* __restrict__ rowmap,
                                                 int* __restrict__ Ms) {
  const int s = blockIdx.x;
  const int tid = threadIdx.x;
  __shared__ int st[160];
  __shared__ int ln[160];
  if (tid < 160) {
    const int b = tid / 5, d = tid % 5;
    ln[tid] = lens[(b * 8 + s) * 5 + d];
  }
  __syncthreads();
  if (tid == 0) {
    int run = 0;
    for (int n = 0; n < 160; ++n) { st[n] = run; run += ln[n]; }
    Ms[s] = run;
  }
  __syncthreads();
  if (tid < 160) {
    const int base = st[tid], l = ln[tid];
    for (int t = 0; t < l; ++t) rowmap[s * 4800 + base + t] = tid * 30 + t;
  }
}

// ---------------------------------------------------------------------------
// K0: split+transpose U via LDS tiles: Uh[s][n][k] = f16(U[s][k][n]);
//     Ul[s][n][k] = f16((U - Uh) * 2048). Coalesced read and write.
// ---------------------------------------------------------------------------
__global__ __launch_bounds__(256) void k0_usplit(const float* __restrict__ U,
                                                 _Float16* __restrict__ Uh,
                                                 _Float16* __restrict__ Ul) {
  const int s = blockIdx.z;
  const int k0 = blockIdx.x * 64;   // 12 tiles over K=768
  const int n0 = blockIdx.y * 64;   // 8 tiles over N=512
  const int tid = threadIdx.x;
  __shared__ _Float16 Th[64 * 66];
  __shared__ _Float16 Tl[64 * 66];
  const float* Us = U + (size_t)s * 768 * 512;
#pragma unroll
  for (int rep = 0; rep < 16; ++rep) {
    const int idx = rep * 256 + tid;
    const int r = idx >> 6, c = idx & 63;
    const float v = Us[(size_t)(k0 + r) * 512 + n0 + c];
    const _Float16 h = (_Float16)v;
    Th[r * 66 + c] = h;
    Tl[r * 66 + c] = (_Float16)((v - (float)h) * 2048.0f);
  }
  __syncthreads();
  _Float16* uhs = Uh + (size_t)s * 512 * 768;
  _Float16* uls = Ul + (size_t)s * 512 * 768;
#pragma unroll
  for (int rep = 0; rep < 8; ++rep) {
    const int idx = rep * 256 + tid;
    const int nn = idx >> 5;           // 0..63
    const int kp = (idx & 31) * 2;     // 0..62 step 2
    const f16x2 h2 = {Th[kp * 66 + nn], Th[(kp + 1) * 66 + nn]};
    const f16x2 l2 = {Tl[kp * 66 + nn], Tl[(kp + 1) * 66 + nn]};
    *(f16x2*)&uhs[(size_t)(n0 + nn) * 768 + k0 + kp] = h2;
    *(f16x2*)&uls[(size_t)(n0 + nn) * 768 + k0 + kp] = l2;
  }
}

// ---------------------------------------------------------------------------
// K1 v3: XU = x @ U + bU via MFMA f32_16x16x32_f16, 2-product fp16 split,
//   row-compacted (only t < len rows), XOR-swizzled LDS (2-way max = free),
//   3 blocks/CU. Tile M128 x N128, K=768 in 24 steps of 32.
// ---------------------------------------------------------------------------
__global__ __launch_bounds__(256, 3) void k1_xu(const float* __restrict__ sent,
                                                const _Float16* __restrict__ Uh,
                                                const _Float16* __restrict__ Ul,
                                                const float* __restrict__ bU,
                                                const int* __restrict__ rowmap,
                                                const int* __restrict__ Ms,
                                                float* __restrict__ XU) {
  const int s = blockIdx.z;
  const int M = Ms[s];
  const int nt = blockIdx.x & 3;
  const int mt = blockIdx.x >> 2;
  if (mt * 128 >= M) return;
  const int tid = threadIdx.x;
  const int lane = tid & 63, wid = tid >> 6;
  const int wm = wid >> 1, wn = wid & 1;

  __shared__ _Float16 Al[2][128 * 32];
  __shared__ _Float16 Bh[2][128 * 32];
  __shared__ _Float16 Bl[2][128 * 32];

  // staging: thread owns logical (row ar1 / ar1+64, 16B-chunk tid&3)
  const int ar1 = tid >> 2;
  const int chk = tid & 3;
  const int afk = chk * 8;
  const int fw = (ar1 ^ (ar1 >> 2)) & 3;          // swizzle key (same for ar1+64)
  const int wA1 = ar1 * 32 + ((chk ^ fw) * 8);    // swizzled half-offset
  const int wA2 = wA1 + 64 * 32;

  const int* rms = rowmap + s * 4800;
  const float* asrc1;
  const float* asrc2;
  {
    int i1 = mt * 128 + ar1; if (i1 > M - 1) i1 = M - 1;
    const int grow = rms[i1];
    const int nn = grow / 30, tt = grow % 30, ab = nn / 5, ad = nn % 5;
    asrc1 = sent + (size_t)((((ab * 8 + s) * 5 + ad) * 30) + tt) * 768 + afk;
  }
  {
    int i2 = mt * 128 + ar1 + 64; if (i2 > M - 1) i2 = M - 1;
    const int grow = rms[i2];
    const int nn = grow / 30, tt = grow % 30, ab = nn / 5, ad = nn % 5;
    asrc2 = sent + (size_t)((((ab * 8 + s) * 5 + ad) * 30) + tt) * 768 + afk;
  }
  const _Float16* UhS = Uh + (size_t)s * 512 * 768;
  const _Float16* UlS = Ul + (size_t)s * 512 * 768;
  const _Float16* bh1 = UhS + (size_t)(nt * 128 + ar1) * 768 + afk;
  const _Float16* bh2 = UhS + (size_t)(nt * 128 + ar1 + 64) * 768 + afk;
  const _Float16* bl1 = UlS + (size_t)(nt * 128 + ar1) * 768 + afk;
  const _Float16* bl2 = UlS + (size_t)(nt * 128 + ar1 + 64) * 768 + afk;

  const _Float16 hsc = (_Float16)0.00048828125f;  // 2^-11
  const f16x8 sc8 = {hsc, hsc, hsc, hsc, hsc, hsc, hsc, hsc};

  // swizzled fragment-read offsets (loop-invariant)
  const int q = lane >> 4;
  const int l15 = lane & 15;
  int aoff[4], boff[4];
#pragma unroll
  for (int f = 0; f < 4; ++f) {
    {
      const int row = wm * 64 + f * 16 + l15;
      const int fr = (row ^ (row >> 2)) & 3;
      aoff[f] = row * 32 + ((q ^ fr) * 8);
    }
    {
      const int row = wn * 64 + f * 16 + l15;
      const int fr = (row ^ (row >> 2)) & 3;
      boff[f] = row * 32 + ((q ^ fr) * 8);
    }
  }

  f32x4 acc[4][4];
#pragma unroll
  for (int i = 0; i < 4; ++i)
#pragma unroll
    for (int j = 0; j < 4; ++j) acc[i][j] = (f32x4){0.f, 0.f, 0.f, 0.f};

  // ---- prologue: stage ks=0 into buf 0 ----
  {
    const float4 a1a = *(const float4*)(asrc1);
    const float4 a1b = *(const float4*)(asrc1 + 4);
    const float4 a2a = *(const float4*)(asrc2);
    const float4 a2b = *(const float4*)(asrc2 + 4);
    const f16x8 vh1 = *(const f16x8*)(bh1);
    const f16x8 vh2 = *(const f16x8*)(bh2);
    const f16x8 vl1 = *(const f16x8*)(bl1);
    const f16x8 vl2 = *(const f16x8*)(bl2);
    f16x8 h1, h2;
    h1[0]=(_Float16)a1a.x; h1[1]=(_Float16)a1a.y; h1[2]=(_Float16)a1a.z; h1[3]=(_Float16)a1a.w;
    h1[4]=(_Float16)a1b.x; h1[5]=(_Float16)a1b.y; h1[6]=(_Float16)a1b.z; h1[7]=(_Float16)a1b.w;
    h2[0]=(_Float16)a2a.x; h2[1]=(_Float16)a2a.y; h2[2]=(_Float16)a2a.z; h2[3]=(_Float16)a2a.w;
    h2[4]=(_Float16)a2b.x; h2[5]=(_Float16)a2b.y; h2[6]=(_Float16)a2b.z; h2[7]=(_Float16)a2b.w;
    *(f16x8*)&Al[0][wA1] = h1;
    *(f16x8*)&Al[0][wA2] = h2;
    *(f16x8*)&Bh[0][wA1] = vh1;
    *(f16x8*)&Bh[0][wA2] = vh2;
    *(f16x8*)&Bl[0][wA1] = vl1;
    *(f16x8*)&Bl[0][wA2] = vl2;
  }
  __syncthreads();

  int cur = 0;
  for (int ks = 0; ks < 24; ++ks) {
    const int nxt = cur ^ 1;
    const bool more = (ks < 23);
    float4 a1a, a1b, a2a, a2b;
    f16x8 vh1, vh2, vl1, vl2;
    if (more) {
      const int ko = (ks + 1) * 32;
      a1a = *(const float4*)(asrc1 + ko);
      a1b = *(const float4*)(asrc1 + ko + 4);
      a2a = *(const float4*)(asrc2 + ko);
      a2b = *(const float4*)(asrc2 + ko + 4);
      vh1 = *(const f16x8*)(bh1 + ko);
      vh2 = *(const f16x8*)(bh2 + ko);
      vl1 = *(const f16x8*)(bl1 + ko);
      vl2 = *(const f16x8*)(bl2 + ko);
    }

    // ---- compute on cur ----
    {
      const _Float16* Ab = &Al[cur][0];
      const _Float16* Bhb = &Bh[cur][0];
      const _Float16* Blb = &Bl[cur][0];
      f16x8 af[4], asf[4], bhf[4], blf[4];
#pragma unroll
      for (int fm = 0; fm < 4; ++fm) {
        af[fm] = *(const f16x8*)&Ab[aoff[fm]];
        asf[fm] = af[fm] * sc8;
      }
#pragma unroll
      for (int fn = 0; fn < 4; ++fn) {
        bhf[fn] = *(const f16x8*)&Bhb[boff[fn]];
        blf[fn] = *(const f16x8*)&Blb[boff[fn]];
      }
#pragma unroll
      for (int fm = 0; fm < 4; ++fm)
#pragma unroll
        for (int fn = 0; fn < 4; ++fn) {
          acc[fm][fn] = __builtin_amdgcn_mfma_f32_16x16x32_f16(af[fm], bhf[fn], acc[fm][fn], 0, 0, 0);
          acc[fm][fn] = __builtin_amdgcn_mfma_f32_16x16x32_f16(asf[fm], blf[fn], acc[fm][fn], 0, 0, 0);
        }
    }

    if (more) {
      f16x8 h1, h2;
      h1[0]=(_Float16)a1a.x; h1[1]=(_Float16)a1a.y; h1[2]=(_Float16)a1a.z; h1[3]=(_Float16)a1a.w;
      h1[4]=(_Float16)a1b.x; h1[5]=(_Float16)a1b.y; h1[6]=(_Float16)a1b.z; h1[7]=(_Float16)a1b.w;
      h2[0]=(_Float16)a2a.x; h2[1]=(_Float16)a2a.y; h2[2]=(_Float16)a2a.z; h2[3]=(_Float16)a2a.w;
      h2[4]=(_Float16)a2b.x; h2[5]=(_Float16)a2b.y; h2[6]=(_Float16)a2b.z; h2[7]=(_Float16)a2b.w;
      *(f16x8*)&Al[nxt][wA1] = h1;
      *(f16x8*)&Al[nxt][wA2] = h2;
      *(f16x8*)&Bh[nxt][wA1] = vh1;
      *(f16x8*)&Bh[nxt][wA2] = vh2;
      *(f16x8*)&Bl[nxt][wA1] = vl1;
      *(f16x8*)&Bl[nxt][wA2] = vl2;
    }
    __syncthreads();
    cur = nxt;
  }

  // ---- epilogue: D[row=(l>>4)*4+r][col=l&15] per frag; add bias; scatter ----
  const int lq = lane >> 4;
  const int colbase = nt * 128 + wn * 64;
  const int ibase = mt * 128 + wm * 64;
  float* XUs = XU + (size_t)s * 4800 * 512;
  int rowm[4][4];
#pragma unroll
  for (int fm = 0; fm < 4; ++fm)
#pragma unroll
    for (int r = 0; r < 4; ++r) {
      const int i = ibase + fm * 16 + lq * 4 + r;
      rowm[fm][r] = (i < M) ? rms[i] : -1;
    }
#pragma unroll
  for (int fn = 0; fn < 4; ++fn) {
    const int col = colbase + fn * 16 + l15;
    const float bias = bU[s * 512 + col];
#pragma unroll
    for (int fm = 0; fm < 4; ++fm)
#pragma unroll
      for (int r = 0; r < 4; ++r) {
        const int row = rowm[fm][r];
        if (row >= 0) XUs[(size_t)row * 512 + col] = acc[fm][fn][r] + bias;
      }
  }
}

// ---------------------------------------------------------------------------
// K2: weight-stationary time-LSTM recurrence (unchanged).
// ---------------------------------------------------------------------------
__global__ __launch_bounds__(512, 2) void k2_tlstm(const float* __restrict__ Wall,
                                                   const float* __restrict__ ball,
                                                   const float* __restrict__ Wd,
                                                   const float* __restrict__ bd,
                                                   const float* __restrict__ XU,
                                                   const float* __restrict__ times,
                                                   const int* __restrict__ lens,
                                                   float* __restrict__ outs,
                                                   float* __restrict__ hn) {
  const int s = blockIdx.y;
  const int bb = blockIdx.x;
  const int n0 = bb * 5;
  const int tid = threadIdx.x;
  const int j = tid & 127;
  const int kg = tid >> 7;

  __shared__ float hsm[5][128];
  __shared__ float csm[5][128];
  __shared__ float red[20][5][128];

  for (int idx = tid; idx < 640; idx += 512) {
    (&hsm[0][0])[idx] = 0.f;
    (&csm[0][0])[idx] = 0.f;
  }

  int len_[5];
  int maxlen = 0;
#pragma unroll
  for (int d = 0; d < 5; ++d) {
    len_[d] = lens[(bb * 8 + s) * 5 + d];
    maxlen = max(maxlen, len_[d]);
  }

  float wall_r[32][4];
  float wd_r[32];
  {
    const float* Wb = Wall + (size_t)s * 65536 + (size_t)(kg * 32) * 512 + j;
    const float* Db = Wd + (size_t)s * 16384 + (size_t)(kg * 32) * 128 + j;
#pragma unroll
    for (int kk = 0; kk < 32; ++kk) {
#pragma unroll
      for (int g = 0; g < 4; ++g) wall_r[kk][g] = Wb[kk * 512 + g * 128];
      wd_r[kk] = Db[kk * 128];
    }
  }

  const float bdj = bd[s * 128 + j];
  float blg[4];
#pragma unroll
  for (int g = 0; g < 4; ++g) blg[g] = ball[s * 512 + g * 128 + j];

  const int sqA = kg;
  const bool hasB = (kg == 0);
  const float* xuAb = XU + (size_t)(s * 160 + n0 + sqA) * 30 * 512 + j;
  const float* xuBb = XU + (size_t)(s * 160 + n0 + 4) * 30 * 512 + j;
  const float* tAb = times + ((size_t)(bb * 8 + s) * 5 + sqA) * 30;
  const float* tBb = times + ((size_t)(bb * 8 + s) * 5 + 4) * 30;
  float* outA = outs + (size_t)(s * 160 + n0 + sqA) * 30 * 128 + j;
  float* outB = outs + (size_t)(s * 160 + n0 + 4) * 30 * 128 + j;

  __syncthreads();

  for (int t = 0; t < maxlen; ++t) {
    float xuA[4], xuB[4];
#pragma unroll
    for (int g = 0; g < 4; ++g) xuA[g] = xuAb[(size_t)t * 512 + g * 128];
    if (hasB) {
#pragma unroll
      for (int g = 0; g < 4; ++g) xuB[g] = xuBb[(size_t)t * 512 + g * 128];
    }

    float acc[5][4] = {};
#pragma unroll
    for (int kk4 = 0; kk4 < 8; ++kk4) {
      float4 h4[5];
#pragma unroll
      for (int sq = 0; sq < 5; ++sq)
        h4[sq] = *(const float4*)&hsm[sq][kg * 32 + kk4 * 4];
#pragma unroll
      for (int u = 0; u < 4; ++u) {
        const int kk = kk4 * 4 + u;
        const float w0 = wall_r[kk][0], w1 = wall_r[kk][1];
        const float w2 = wall_r[kk][2], w3 = wall_r[kk][3];
#pragma unroll
        for (int sq = 0; sq < 5; ++sq) {
          const float hv = ((const float*)&h4[sq])[u];
          acc[sq][0] += hv * w0; acc[sq][1] += hv * w1;
          acc[sq][2] += hv * w2; acc[sq][3] += hv * w3;
        }
      }
    }
    float pd[5] = {};
#pragma unroll
    for (int kk4 = 0; kk4 < 8; ++kk4) {
      float4 c4[5];
#pragma unroll
      for (int sq = 0; sq < 5; ++sq)
        c4[sq] = *(const float4*)&csm[sq][kg * 32 + kk4 * 4];
#pragma unroll
      for (int u = 0; u < 4; ++u) {
        const int kk = kk4 * 4 + u;
        const float wd = wd_r[kk];
#pragma unroll
        for (int sq = 0; sq < 5; ++sq)
          pd[sq] += ((const float*)&c4[sq])[u] * wd;
      }
    }
#pragma unroll
    for (int g = 0; g < 4; ++g)
#pragma unroll
      for (int sq = 0; sq < 5; ++sq) red[g * 4 + kg][sq][j] = acc[sq][g];
#pragma unroll
    for (int sq = 0; sq < 5; ++sq) red[16 + kg][sq][j] = pd[sq];
    __syncthreads();

    {
      const int sq = sqA;
      if (t < len_[sq]) {
        float g4[4];
#pragma unroll
        for (int g = 0; g < 4; ++g)
          g4[g] = red[g * 4 + 0][sq][j] + red[g * 4 + 1][sq][j] +
                  red[g * 4 + 2][sq][j] + red[g * 4 + 3][sq][j] + blg[g] + xuA[g];
        float cs1 = red[16][sq][j] + red[17][sq][j] + red[18][sq][j] + red[19][sq][j] + bdj;
        cs1 = tanhf_(cs1);
        const float tt = tAb[t];
        const float f = sigf(g4[0]), ii = sigf(g4[1]);
        const float o = sigf(g4[2]), ct = sigf(g4[3]);
        const float cc = csm[sq][j];
        const float c2 = f * (cc + cs1 * (tt - 1.f)) + ii * ct;
        const float h2 = o * tanhf_(c2);
        csm[sq][j] = c2;
        hsm[sq][j] = h2;
        outA[(size_t)t * 128] = o;
        if (t == len_[sq] - 1) hn[(size_t)(s * 160 + n0 + sq) * 128 + j] = o;
      }
    }
    if (hasB) {
      const int sq = 4;
      if (t < len_[sq]) {
        float g4[4];
#pragma unroll
        for (int g = 0; g < 4; ++g)
          g4[g] = red[g * 4 + 0][sq][j] + red[g * 4 + 1][sq][j] +
                  red[g * 4 + 2][sq][j] + red[g * 4 + 3][sq][j] + blg[g] + xuB[g];
        float cs1 = red[16][sq][j] + red[17][sq][j] + red[18][sq][j] + red[19][sq][j] + bdj;
        cs1 = tanhf_(cs1);
        const float tt = tBb[t];
        const float f = sigf(g4[0]), ii = sigf(g4[1]);
        const float o = sigf(g4[2]), ct = sigf(g4[3]);
        const float cc = csm[sq][j];
        const float c2 = f * (cc + cs1 * (tt - 1.f)) + ii * ct;
        const float h2 = o * tanhf_(c2);
        csm[sq][j] = c2;
        hsm[sq][j] = h2;
        outB[(size_t)t * 128] = o;
        if (t == len_[sq] - 1) hn[(size_t)(s * 160 + n0 + sq) * 128 + j] = o;
      }
    }
    __syncthreads();
  }
}

// ---------------------------------------------------------------------------
// K3: attention 1, per-wave t-scores.
// ---------------------------------------------------------------------------
__global__ __launch_bounds__(128) void k3_attn1(const float* __restrict__ W1,
                                                const float* __restrict__ b1,
                                                const float* __restrict__ W2,
                                                const float* __restrict__ b2,
                                                const float* __restrict__ V,
                                                const float* __restrict__ bV,
                                                const float* __restrict__ outs,
                                                const float* __restrict__ hn,
                                                const int* __restrict__ lens,
                                                float* __restrict__ ctx) {
  const int s = blockIdx.y, n = blockIdx.x, j = threadIdx.x;
  const int b = n / 5, d = n % 5;
  const int len = lens[(b * 8 + s) * 5 + d];
  __shared__ float os[30][128];
  __shared__ float hns[128];
  __shared__ float u_sh[128];
  __shared__ float score[30];

  hns[j] = hn[(size_t)(s * 160 + n) * 128 + j];
  const float* og = outs + (size_t)(s * 160 + n) * 30 * 128;
  for (int idx = j; idx < len * 128; idx += 128) (&os[0][0])[idx] = og[idx];
  __syncthreads();

  const float* W1s = W1 + (size_t)s * 16384;
  float u = b1[s * 128 + j] + b2[s * 128 + j];
  for (int k = 0; k < 128; ++k) u += hns[k] * W1s[k * 128 + j];
  u_sh[j] = u;
  __syncthreads();

  const float* W2s = W2 + (size_t)s * 16384;
  const float bVs = bV[s];
  const int lane = j & 63, wid = j >> 6;
  const float V0 = V[s * 128 + lane], V1 = V[s * 128 + 64 + lane];

  for (int t = wid; t < len; t += 2) {
    float a0 = u_sh[lane], a1 = u_sh[64 + lane];
    for (int k = 0; k < 128; ++k) {
      const float ok = os[t][k];
      a0 += ok * W2s[k * 128 + lane];
      a1 += ok * W2s[k * 128 + 64 + lane];
    }
    float p = tanhf_(a0) * V0 + tanhf_(a1) * V1;
#pragma unroll
    for (int off = 32; off; off >>= 1) p += __shfl_down(p, off);
    if (lane == 0) score[t] = p + bVs;
  }
  __syncthreads();

  float m = -1e30f;
  for (int t = 0; t < len; ++t) m = fmaxf(m, score[t]);
  float sum = 0.f;
  for (int t = 0; t < len; ++t) sum += __expf(score[t] - m);
  float cx = 0.f;
  for (int t = 0; t < len; ++t) cx += __expf(score[t] - m) * os[t][j];
  ctx[(size_t)(s * 160 + n) * 128 + j] = cx / sum;
}

// ---------------------------------------------------------------------------
// K4: LSTM over D=5, 512 threads, Whh reg-stationary. Gate order i,f,g,o.
// ---------------------------------------------------------------------------
__global__ __launch_bounds__(512) void k4_lstm2(const float* __restrict__ Wih,
                                                const float* __restrict__ bih,
                                                const float* __restrict__ Whh,
                                                const float* __restrict__ bhh,
                                                const float* __restrict__ ctx,
                                                float* __restrict__ hsout,
                                                float* __restrict__ hlast) {
  const int s = blockIdx.y, b = blockIdx.x;
  const int gj = threadIdx.x;
  __shared__ float xs[5][128];
  __shared__ float hsm[128];
  __shared__ float gsh[512];

  for (int idx = gj; idx < 640; idx += 512)
    (&xs[0][0])[idx] = ctx[(size_t)(s * 160 + b * 5) * 128 + idx];
  if (gj < 128) hsm[gj] = 0.f;
  __syncthreads();

  const float* Wis = Wih + (size_t)s * 65536;
  const float* Whs = Whh + (size_t)s * 65536;
  const float bias = bih[s * 512 + gj] + bhh[s * 512 + gj];
  float xw[5] = {bias, bias, bias, bias, bias};
  float whh[128];
#pragma unroll
  for (int k = 0; k < 128; ++k) {
    const float wi = Wis[k * 512 + gj];
    whh[k] = Whs[k * 512 + gj];
#pragma unroll
    for (int dd = 0; dd < 5; ++dd) xw[dd] += xs[dd][k] * wi;
  }

  float c = 0.f;
  for (int dd = 0; dd < 5; ++dd) {
    float g = xw[dd];
#pragma unroll
    for (int k = 0; k < 128; ++k) g += hsm[k] * whh[k];
    gsh[gj] = g;
    __syncthreads();
    if (gj < 128) {
      const int j = gj;
      const float c2 = sigf(gsh[128 + j]) * c + sigf(gsh[j]) * tanhf_(gsh[256 + j]);
      const float h2 = sigf(gsh[384 + j]) * tanhf_(c2);
      c = c2;
      hsm[j] = h2;
      hsout[((size_t)(s * 32 + b) * 5 + dd) * 128 + j] = h2;
      if (dd == 4) hlast[(size_t)(s * 32 + b) * 128 + j] = h2;
    }
    __syncthreads();
  }
}

// ---------------------------------------------------------------------------
// K5: attention 2 (no mask, D=5) + y = relu(ctx2@x1W+x1b)@x2W+x2b.
// ---------------------------------------------------------------------------
__global__ __launch_bounds__(128) void k5_attn2(const float* __restrict__ W1,
                                                const float* __restrict__ b1,
                                                const float* __restrict__ W2,
                                                const float* __restrict__ b2,
                                                const float* __restrict__ V,
                                                const float* __restrict__ bV,
                                                const float* __restrict__ x1W,
                                                const float* __restrict__ x1b,
                                                const float* __restrict__ x2W,
                                                const float* __restrict__ x2b,
                                                const float* __restrict__ hs,
                                                const float* __restrict__ hlast,
                                                float* __restrict__ y) {
  const int s = blockIdx.y, b = blockIdx.x, j = threadIdx.x;
  __shared__ float hl[128], hsm[5][128], t1[128], cs2[128], sc[5], red[2];
  hl[j] = hlast[(size_t)(s * 32 + b) * 128 + j];
  const float* hsrc = hs + (size_t)(s * 32 + b) * 640;
  for (int idx = j; idx < 640; idx += 128) (&hsm[0][0])[idx] = hsrc[idx];
  __syncthreads();

  const float* W1s = W1 + (size_t)s * 16384;
  const float* W2s = W2 + (size_t)s * 16384;
  float u = b1[s * 128 + j] + b2[s * 128 + j];
  for (int k = 0; k < 128; ++k) u += hl[k] * W1s[k * 128 + j];
  const float Vj = V[s * 128 + j];
  const int lane = j & 63, wid = j >> 6;

  for (int d = 0; d < 5; ++d) {
    float a = u;
    for (int k = 0; k < 128; ++k) a += hsm[d][k] * W2s[k * 128 + j];
    float p = tanhf_(a) * Vj;
#pragma unroll
    for (int off = 32; off; off >>= 1) p += __shfl_down(p, off);
    if (lane == 0) red[wid] = p;
    __syncthreads();
    if (j == 0) sc[d] = red[0] + red[1] + bV[s];
    __syncthreads();
  }

  float m = -1e30f;
  for (int d = 0; d < 5; ++d) m = fmaxf(m, sc[d]);
  float sum = 0.f;
  for (int d = 0; d < 5; ++d) sum += __expf(sc[d] - m);
  float cx = 0.f;
  for (int d = 0; d < 5; ++d) cx += __expf(sc[d] - m) * hsm[d][j];
  cs2[j] = cx / sum;
  __syncthreads();

  float a = x1b[s * 128 + j];
  for (int k = 0; k < 128; ++k) a += cs2[k] * x1W[(size_t)s * 16384 + k * 128 + j];
  t1[j] = fmaxf(a, 0.f);
  __syncthreads();

  if (j < 64) {
    float yy = x2b[s * 64 + j];
    for (int k = 0; k < 128; ++k) yy += t1[k] * x2W[(size_t)(s * 128 + k) * 64 + j];
    y[(size_t)(s * 32 + b) * 64 + j] = yy;
  }
}

// ---------------------------------------------------------------------------
// K6: final combine.
// ---------------------------------------------------------------------------
__global__ __launch_bounds__(256) void k6_final(const float* __restrict__ stock,
                                                const float* __restrict__ h1W,
                                                const float* __restrict__ h1b,
                                                const float* __restrict__ h2W,
                                                const float* __restrict__ h2b,
                                                const float* __restrict__ hcW,
                                                const float* __restrict__ hcb,
                                                const float* __restrict__ yws,
                                                float* __restrict__ out) {
  const int tid = threadIdx.x;
  __shared__ float sf[32 * 17];
  __shared__ float hid[32 * 64];
  __shared__ float xs[32 * 32];
  for (int idx = tid; idx < 544; idx += 256) sf[idx] = stock[idx];
  __syncthreads();
  for (int idx = tid; idx < 2048; idx += 256) {
    const int b = idx >> 6, k = idx & 63;
    float a = h1b[k];
    for (int q = 0; q < 17; ++q) a += sf[b * 17 + q] * h1W[q * 64 + k];
    hid[idx] = fmaxf(a, 0.f);
  }
  __syncthreads();
  for (int idx = tid; idx < 1024; idx += 256) {
    const int b = idx >> 5, mm = idx & 31;
    float a = h2b[mm];
    for (int k = 0; k < 64; ++k) a += hid[b * 64 + k] * h2W[k * 32 + mm];
    xs[idx] = a;
  }
  __syncthreads();
  {
    const int b = tid >> 3, o = tid & 7;
    float a = hcb[o];
    for (int c = 0; c < 32; ++c) a += xs[b * 32 + c] * hcW[c * 8 + o];
    for (int c = 32; c < 544; ++c) {
      const int ss = (c - 32) >> 6, k = (c - 32) & 63;
      a += yws[((size_t)ss * 32 + b) * 64 + k] * hcW[c * 8 + o];
    }
    out[tid] = tanhf_(a);
  }
}

// ---------------------------------------------------------------------------
extern "C" void kernel_launch(void* const* d_in, const int* in_sizes, int n_in,
                              void* d_out, int out_size, void* d_ws, size_t ws_size,
                              hipStream_t stream) {
  (void)in_sizes; (void)n_in; (void)out_size; (void)ws_size;
  const float* stock = (const float*)d_in[0];
  const float* sent  = (const float*)d_in[1];
  const float* times = (const float*)d_in[2];
  const int*   lens  = (const int*)d_in[3];
  const float* tlWall = (const float*)d_in[4];
  const float* tlball = (const float*)d_in[5];
  const float* tlUall = (const float*)d_in[6];
  const float* tlbU   = (const float*)d_in[7];
  const float* tlWd   = (const float*)d_in[8];
  const float* tlbd   = (const float*)d_in[9];
  const float* a1W1 = (const float*)d_in[10];
  const float* a1b1 = (const float*)d_in[11];
  const float* a1W2 = (const float*)d_in[12];
  const float* a1b2 = (const float*)d_in[13];
  const float* a1V  = (const float*)d_in[14];
  const float* a1bV = (const float*)d_in[15];
  const float* l2Wih = (const float*)d_in[16];
  const float* l2bih = (const float*)d_in[17];
  const float* l2Whh = (const float*)d_in[18];
  const float* l2bhh = (const float*)d_in[19];
  const float* a2W1 = (const float*)d_in[20];
  const float* a2b1 = (const float*)d_in[21];
  const float* a2W2 = (const float*)d_in[22];
  const float* a2b2 = (const float*)d_in[23];
  const float* a2V  = (const float*)d_in[24];
  const float* a2bV = (const float*)d_in[25];
  const float* x1W  = (const float*)d_in[26];
  const float* x1b  = (const float*)d_in[27];
  const float* x2W  = (const float*)d_in[28];
  const float* x2b  = (const float*)d_in[29];
  const float* h1W  = (const float*)d_in[30];
  const float* h1b  = (const float*)d_in[31];
  const float* h2W  = (const float*)d_in[32];
  const float* h2b  = (const float*)d_in[33];
  const float* hcW  = (const float*)d_in[34];
  const float* hcb  = (const float*)d_in[35];

  float* ws = (float*)d_ws;
  float* XU    = ws;               // 8*160*30*512   = 19,660,800
  float* outs  = XU + 19660800;    // 8*160*30*128   =  4,915,200
  float* hnb   = outs + 4915200;   // 8*160*128      =    163,840
  float* ctx   = hnb + 163840;     // 8*160*128      =    163,840
  float* hsb   = ctx + 163840;     // 8*32*5*128     =    163,840
  float* hlast = hsb + 163840;     // 8*32*128       =     32,768
  float* yb    = hlast + 32768;    // 8*32*64        =     16,384
  _Float16* Uhw = (_Float16*)(yb + 16384);   // 8*512*768 halfs
  _Float16* Ulw = Uhw + 8 * 512 * 768;       // 8*512*768 halfs
  int* rowmap = (int*)(Ulw + 8 * 512 * 768); // 8*4800 ints
  int* Msd    = rowmap + 8 * 4800;           // 8 ints

  k0_rowmap<<<8, 256, 0, stream>>>(lens, rowmap, Msd);
  k0_usplit<<<dim3(12, 8, 8), 256, 0, stream>>>(tlUall, Uhw, Ulw);
  k1_xu<<<dim3(152, 1, 8), 256, 0, stream>>>(sent, Uhw, Ulw, tlbU, rowmap, Msd, XU);
  k2_tlstm<<<dim3(32, 8), 512, 0, stream>>>(tlWall, tlball, tlWd, tlbd, XU, times, lens, outs, hnb);
  k3_attn1<<<dim3(160, 8), 128, 0, stream>>>(a1W1, a1b1, a1W2, a1b2, a1V, a1bV, outs, hnb, lens, ctx);
  k4_lstm2<<<dim3(32, 8), 512, 0, stream>>>(l2Wih, l2bih, l2Whh, l2bhh, ctx, hsb, hlast);
  k5_attn2<<<dim3(32, 8), 128, 0, stream>>>(a2W1, a2b1, a2W2, a2b2, a2V, a2bV, x1W, x1b, x2W, x2b, hsb, hlast, yb);
  k6_final<<<1, 256, 0, stream>>>(stock, h1W, h1b, h2W, h2b, hcW, hcb, yb, (float*)d_out);
}

// Round 5
// 328.802 us; speedup vs baseline: 4.0102x; 1.0266x over previous
//
#include <hip/hip_runtime.h>
#include <cstddef>

// Problem constants: S=8, B=32, D=5, T=30, E=768, H=128, 4H=512.

typedef __attribute__((ext_vector_type(8))) _Float16 f16x8;
typedef __attribute__((ext_vector_type(4))) _Float16 f16x4;
typedef __attribute__((ext_vector_type(2))) _Float16 f16x2;
typedef __attribute__((ext_vector_type(4))) float f32x4;

__device__ __forceinline__ float sigf(float x) { return 1.0f / (1.0f + __expf(-x)); }
__device__ __forceinline__ float tanhf_(float x) { return 1.0f - 2.0f / (__expf(2.0f * x) + 1.0f); }

// ---------------------------------------------------------------------------
// K0r: per-stock compacted row map: rows (n,t) with t < len[s,n].
// ---------------------------------------------------------------------------
__global__ __launch_bounds__(256) void k0_rowmap(const int* __restrict__ lens,
                                                 int* __restrict__ rowmap,
                                                 int* __restrict__ Ms) {
  const int s = blockIdx.x;
  const int tid = threadIdx.x;
  __shared__ int st[160];
  __shared__ int ln[160];
  if (tid < 160) {
    const int b = tid / 5, d = tid % 5;
    ln[tid] = lens[(b * 8 + s) * 5 + d];
  }
  __syncthreads();
  if (tid == 0) {
    int run = 0;
    for (int n = 0; n < 160; ++n) { st[n] = run; run += ln[n]; }
    Ms[s] = run;
  }
  __syncthreads();
  if (tid < 160) {
    const int base = st[tid], l = ln[tid];
    for (int t = 0; t < l; ++t) rowmap[s * 4800 + base + t] = tid * 30 + t;
  }
}

// ---------------------------------------------------------------------------
// K0: split+transpose U via LDS tiles (for k1).
// ---------------------------------------------------------------------------
__global__ __launch_bounds__(256) void k0_usplit(const float* __restrict__ U,
                                                 _Float16* __restrict__ Uh,
                                                 _Float16* __restrict__ Ul) {
  const int s = blockIdx.z;
  const int k0 = blockIdx.x * 64;
  const int n0 = blockIdx.y * 64;
  const int tid = threadIdx.x;
  __shared__ _Float16 Th[64 * 66];
  __shared__ _Float16 Tl[64 * 66];
  const float* Us = U + (size_t)s * 768 * 512;
#pragma unroll
  for (int rep = 0; rep < 16; ++rep) {
    const int idx = rep * 256 + tid;
    const int r = idx >> 6, c = idx & 63;
    const float v = Us[(size_t)(k0 + r) * 512 + n0 + c];
    const _Float16 h = (_Float16)v;
    Th[r * 66 + c] = h;
    Tl[r * 66 + c] = (_Float16)((v - (float)h) * 2048.0f);
  }
  __syncthreads();
  _Float16* uhs = Uh + (size_t)s * 512 * 768;
  _Float16* uls = Ul + (size_t)s * 512 * 768;
#pragma unroll
  for (int rep = 0; rep < 8; ++rep) {
    const int idx = rep * 256 + tid;
    const int nn = idx >> 5;
    const int kp = (idx & 31) * 2;
    const f16x2 h2 = {Th[kp * 66 + nn], Th[(kp + 1) * 66 + nn]};
    const f16x2 l2 = {Tl[kp * 66 + nn], Tl[(kp + 1) * 66 + nn]};
    *(f16x2*)&uhs[(size_t)(n0 + nn) * 768 + k0 + kp] = h2;
    *(f16x2*)&uls[(size_t)(n0 + nn) * 768 + k0 + kp] = l2;
  }
}

// ---------------------------------------------------------------------------
// K0w: pack Wall (hi+lo split) and Wd (hi) into MFMA B-fragment-linear layout.
//   Wfh/Wfl[(s*8+w)*8192 + ((kt*4+nt)*64 + l)*8 + e] = f16(Wall[s][k][n])
//     with n = w*64+nt*16+(l&15), k = kt*32+((l>>4)<<3)+e.
//   Dfh[(s*8+w)*2048 + (kt*64+l)*8 + e] = f16(Wd[s][k][n]), n = w*16+(l&15).
// ---------------------------------------------------------------------------
__global__ __launch_bounds__(256) void k0_wprep(const float* __restrict__ Wall,
                                                const float* __restrict__ Wd,
                                                _Float16* __restrict__ Wfh,
                                                _Float16* __restrict__ Wfl,
                                                _Float16* __restrict__ Dfh) {
  const int w = blockIdx.x, s = blockIdx.y;
  const int tid = threadIdx.x;
  const float* Ws = Wall + (size_t)s * 65536;
  _Float16* oh = Wfh + (size_t)(s * 8 + w) * 8192;
  _Float16* ol = Wfl + (size_t)(s * 8 + w) * 8192;
  for (int c = tid; c < 1024; c += 256) {
    const int kt = c >> 8, nt = (c >> 6) & 3, l = c & 63;
    const int n = w * 64 + nt * 16 + (l & 15);
    const int kb = kt * 32 + ((l >> 4) << 3);
    f16x8 hv, lv;
#pragma unroll
    for (int e = 0; e < 8; ++e) {
      const float v = Ws[(size_t)(kb + e) * 512 + n];
      const _Float16 h = (_Float16)v;
      hv[e] = h;
      lv[e] = (_Float16)((v - (float)h) * 2048.0f);
    }
    *(f16x8*)&oh[c * 8] = hv;
    *(f16x8*)&ol[c * 8] = lv;
  }
  {
    const float* Ds = Wd + (size_t)s * 16384;
    _Float16* od = Dfh + (size_t)(s * 8 + w) * 2048;
    const int c = tid;
    const int kt = c >> 6, l = c & 63;
    const int n = w * 16 + (l & 15);
    const int kb = kt * 32 + ((l >> 4) << 3);
    f16x8 hv;
#pragma unroll
    for (int e = 0; e < 8; ++e) hv[e] = (_Float16)Ds[(size_t)(kb + e) * 128 + n];
    *(f16x8*)&od[c * 8] = hv;
  }
}

// ---------------------------------------------------------------------------
// K1 v3: XU = x @ U + bU via MFMA, 2-product fp16 split, row-compacted,
//   XOR-swizzled LDS, 3 blocks/CU. (unchanged from round 4)
// ---------------------------------------------------------------------------
__global__ __launch_bounds__(256, 3) void k1_xu(const float* __restrict__ sent,
                                                const _Float16* __restrict__ Uh,
                                                const _Float16* __restrict__ Ul,
                                                const float* __restrict__ bU,
                                                const int* __restrict__ rowmap,
                                                const int* __restrict__ Ms,
                                                float* __restrict__ XU) {
  const int s = blockIdx.z;
  const int M = Ms[s];
  const int nt = blockIdx.x & 3;
  const int mt = blockIdx.x >> 2;
  if (mt * 128 >= M) return;
  const int tid = threadIdx.x;
  const int lane = tid & 63, wid = tid >> 6;
  const int wm = wid >> 1, wn = wid & 1;

  __shared__ _Float16 Al[2][128 * 32];
  __shared__ _Float16 Bh[2][128 * 32];
  __shared__ _Float16 Bl[2][128 * 32];

  const int ar1 = tid >> 2;
  const int chk = tid & 3;
  const int afk = chk * 8;
  const int fw = (ar1 ^ (ar1 >> 2)) & 3;
  const int wA1 = ar1 * 32 + ((chk ^ fw) * 8);
  const int wA2 = wA1 + 64 * 32;

  const int* rms = rowmap + s * 4800;
  const float* asrc1;
  const float* asrc2;
  {
    int i1 = mt * 128 + ar1; if (i1 > M - 1) i1 = M - 1;
    const int grow = rms[i1];
    const int nn = grow / 30, tt = grow % 30, ab = nn / 5, ad = nn % 5;
    asrc1 = sent + (size_t)((((ab * 8 + s) * 5 + ad) * 30) + tt) * 768 + afk;
  }
  {
    int i2 = mt * 128 + ar1 + 64; if (i2 > M - 1) i2 = M - 1;
    const int grow = rms[i2];
    const int nn = grow / 30, tt = grow % 30, ab = nn / 5, ad = nn % 5;
    asrc2 = sent + (size_t)((((ab * 8 + s) * 5 + ad) * 30) + tt) * 768 + afk;
  }
  const _Float16* UhS = Uh + (size_t)s * 512 * 768;
  const _Float16* UlS = Ul + (size_t)s * 512 * 768;
  const _Float16* bh1 = UhS + (size_t)(nt * 128 + ar1) * 768 + afk;
  const _Float16* bh2 = UhS + (size_t)(nt * 128 + ar1 + 64) * 768 + afk;
  const _Float16* bl1 = UlS + (size_t)(nt * 128 + ar1) * 768 + afk;
  const _Float16* bl2 = UlS + (size_t)(nt * 128 + ar1 + 64) * 768 + afk;

  const _Float16 hsc = (_Float16)0.00048828125f;  // 2^-11
  const f16x8 sc8 = {hsc, hsc, hsc, hsc, hsc, hsc, hsc, hsc};

  const int q = lane >> 4;
  const int l15 = lane & 15;
  int aoff[4], boff[4];
#pragma unroll
  for (int f = 0; f < 4; ++f) {
    {
      const int row = wm * 64 + f * 16 + l15;
      const int fr = (row ^ (row >> 2)) & 3;
      aoff[f] = row * 32 + ((q ^ fr) * 8);
    }
    {
      const int row = wn * 64 + f * 16 + l15;
      const int fr = (row ^ (row >> 2)) & 3;
      boff[f] = row * 32 + ((q ^ fr) * 8);
    }
  }

  f32x4 acc[4][4];
#pragma unroll
  for (int i = 0; i < 4; ++i)
#pragma unroll
    for (int j = 0; j < 4; ++j) acc[i][j] = (f32x4){0.f, 0.f, 0.f, 0.f};

  {
    const float4 a1a = *(const float4*)(asrc1);
    const float4 a1b = *(const float4*)(asrc1 + 4);
    const float4 a2a = *(const float4*)(asrc2);
    const float4 a2b = *(const float4*)(asrc2 + 4);
    const f16x8 vh1 = *(const f16x8*)(bh1);
    const f16x8 vh2 = *(const f16x8*)(bh2);
    const f16x8 vl1 = *(const f16x8*)(bl1);
    const f16x8 vl2 = *(const f16x8*)(bl2);
    f16x8 h1, h2;
    h1[0]=(_Float16)a1a.x; h1[1]=(_Float16)a1a.y; h1[2]=(_Float16)a1a.z; h1[3]=(_Float16)a1a.w;
    h1[4]=(_Float16)a1b.x; h1[5]=(_Float16)a1b.y; h1[6]=(_Float16)a1b.z; h1[7]=(_Float16)a1b.w;
    h2[0]=(_Float16)a2a.x; h2[1]=(_Float16)a2a.y; h2[2]=(_Float16)a2a.z; h2[3]=(_Float16)a2a.w;
    h2[4]=(_Float16)a2b.x; h2[5]=(_Float16)a2b.y; h2[6]=(_Float16)a2b.z; h2[7]=(_Float16)a2b.w;
    *(f16x8*)&Al[0][wA1] = h1;
    *(f16x8*)&Al[0][wA2] = h2;
    *(f16x8*)&Bh[0][wA1] = vh1;
    *(f16x8*)&Bh[0][wA2] = vh2;
    *(f16x8*)&Bl[0][wA1] = vl1;
    *(f16x8*)&Bl[0][wA2] = vl2;
  }
  __syncthreads();

  int cur = 0;
  for (int ks = 0; ks < 24; ++ks) {
    const int nxt = cur ^ 1;
    const bool more = (ks < 23);
    float4 a1a, a1b, a2a, a2b;
    f16x8 vh1, vh2, vl1, vl2;
    if (more) {
      const int ko = (ks + 1) * 32;
      a1a = *(const float4*)(asrc1 + ko);
      a1b = *(const float4*)(asrc1 + ko + 4);
      a2a = *(const float4*)(asrc2 + ko);
      a2b = *(const float4*)(asrc2 + ko + 4);
      vh1 = *(const f16x8*)(bh1 + ko);
      vh2 = *(const f16x8*)(bh2 + ko);
      vl1 = *(const f16x8*)(bl1 + ko);
      vl2 = *(const f16x8*)(bl2 + ko);
    }
    {
      const _Float16* Ab = &Al[cur][0];
      const _Float16* Bhb = &Bh[cur][0];
      const _Float16* Blb = &Bl[cur][0];
      f16x8 af[4], asf[4], bhf[4], blf[4];
#pragma unroll
      for (int fm = 0; fm < 4; ++fm) {
        af[fm] = *(const f16x8*)&Ab[aoff[fm]];
        asf[fm] = af[fm] * sc8;
      }
#pragma unroll
      for (int fn = 0; fn < 4; ++fn) {
        bhf[fn] = *(const f16x8*)&Bhb[boff[fn]];
        blf[fn] = *(const f16x8*)&Blb[boff[fn]];
      }
#pragma unroll
      for (int fm = 0; fm < 4; ++fm)
#pragma unroll
        for (int fn = 0; fn < 4; ++fn) {
          acc[fm][fn] = __builtin_amdgcn_mfma_f32_16x16x32_f16(af[fm], bhf[fn], acc[fm][fn], 0, 0, 0);
          acc[fm][fn] = __builtin_amdgcn_mfma_f32_16x16x32_f16(asf[fm], blf[fn], acc[fm][fn], 0, 0, 0);
        }
    }
    if (more) {
      f16x8 h1, h2;
      h1[0]=(_Float16)a1a.x; h1[1]=(_Float16)a1a.y; h1[2]=(_Float16)a1a.z; h1[3]=(_Float16)a1a.w;
      h1[4]=(_Float16)a1b.x; h1[5]=(_Float16)a1b.y; h1[6]=(_Float16)a1b.z; h1[7]=(_Float16)a1b.w;
      h2[0]=(_Float16)a2a.x; h2[1]=(_Float16)a2a.y; h2[2]=(_Float16)a2a.z; h2[3]=(_Float16)a2a.w;
      h2[4]=(_Float16)a2b.x; h2[5]=(_Float16)a2b.y; h2[6]=(_Float16)a2b.z; h2[7]=(_Float16)a2b.w;
      *(f16x8*)&Al[nxt][wA1] = h1;
      *(f16x8*)&Al[nxt][wA2] = h2;
      *(f16x8*)&Bh[nxt][wA1] = vh1;
      *(f16x8*)&Bh[nxt][wA2] = vh2;
      *(f16x8*)&Bl[nxt][wA1] = vl1;
      *(f16x8*)&Bl[nxt][wA2] = vl2;
    }
    __syncthreads();
    cur = nxt;
  }

  const int lq = lane >> 4;
  const int colbase = nt * 128 + wn * 64;
  const int ibase = mt * 128 + wm * 64;
  float* XUs = XU + (size_t)s * 4800 * 512;
  int rowm[4][4];
#pragma unroll
  for (int fm = 0; fm < 4; ++fm)
#pragma unroll
    for (int r = 0; r < 4; ++r) {
      const int i = ibase + fm * 16 + lq * 4 + r;
      rowm[fm][r] = (i < M) ? rms[i] : -1;
    }
#pragma unroll
  for (int fn = 0; fn < 4; ++fn) {
    const int col = colbase + fn * 16 + l15;
    const float bias = bU[s * 512 + col];
#pragma unroll
    for (int fm = 0; fm < 4; ++fm)
#pragma unroll
      for (int r = 0; r < 4; ++r) {
        const int row = rowm[fm][r];
        if (row >= 0) XUs[(size_t)row * 512 + col] = acc[fm][fn][r] + bias;
      }
  }
}

// ---------------------------------------------------------------------------
// K2 v3: MFMA time-LSTM. 80 blocks = (10 groups of 16 seqs) x 8 stocks.
//   512 thr = 8 waves; wave w holds Wall cols [w*64,w*64+64) as hi+lo f16
//   B-frags and Wd cols [w*16,+16) hi-only, register-stationary.
//   Per step: phase M = 52 MFMA/wave -> pre/pred LDS; phase E = gates +
//   elementwise + h/c -> f16 fragment conversion. 2 barriers/step.
//   Gate order f,i,o,ct (all sigmoid); c_adj = c + cs1*(tt-1); emit o.
// ---------------------------------------------------------------------------
__global__ __launch_bounds__(512, 2) void k2_tlstm(const _Float16* __restrict__ Wfh,
                                                   const _Float16* __restrict__ Wfl,
                                                   const _Float16* __restrict__ Dfh,
                                                   const float* __restrict__ ball,
                                                   const float* __restrict__ bd,
                                                   const float* __restrict__ XU,
                                                   const float* __restrict__ times,
                                                   const int* __restrict__ lens,
                                                   float* __restrict__ outs,
                                                   float* __restrict__ hn) {
  const int s = blockIdx.y;
  const int mg = blockIdx.x;
  const int tid = threadIdx.x;
  const int w = tid >> 6, l = tid & 63;

  __shared__ float csm[16 * 128];
  __shared__ _Float16 hh[2048], hl[2048], chs[2048];
  __shared__ float pre[16 * 516];
  __shared__ float pred[16 * 132];
  __shared__ int lensh[16];

  for (int i = tid; i < 2048; i += 512) {
    csm[i] = 0.f;
    hh[i] = (_Float16)0.f;
    hl[i] = (_Float16)0.f;
    chs[i] = (_Float16)0.f;
  }
  if (tid < 16) {
    const int n = mg * 16 + tid;
    const int b = n / 5, dd = n % 5;
    lensh[tid] = lens[(b * 8 + s) * 5 + dd];
  }
  __syncthreads();
  int maxlen = 0;
#pragma unroll
  for (int i = 0; i < 16; ++i) maxlen = max(maxlen, lensh[i]);

  // ---- register-stationary weight fragments ----
  f16x8 Bh[16], Bl[16], Dh[4];
  {
    const _Float16* wb = Wfh + (size_t)(s * 8 + w) * 8192 + l * 8;
    const _Float16* lb = Wfl + (size_t)(s * 8 + w) * 8192 + l * 8;
    const _Float16* db = Dfh + (size_t)(s * 8 + w) * 2048 + l * 8;
#pragma unroll
    for (int c = 0; c < 16; ++c) {
      Bh[c] = *(const f16x8*)&wb[c * 512];
      Bl[c] = *(const f16x8*)&lb[c * 512];
    }
#pragma unroll
    for (int c = 0; c < 4; ++c) Dh[c] = *(const f16x8*)&db[c * 512];
  }

  // ---- phase-E per-thread constants ----
  const int r = tid >> 5, j0 = (tid & 31) * 4;
  const int n = mg * 16 + r;
  const int b = n / 5, dd = n % 5;
  const int len_r = lensh[r];
  const float* xu = XU + (size_t)(s * 160 + n) * 30 * 512 + j0;
  float* outp = outs + (size_t)(s * 160 + n) * 30 * 128 + j0;
  float* hnp = hn + (size_t)(s * 160 + n) * 128 + j0;
  const float* tp = times + ((size_t)(b * 8 + s) * 5 + dd) * 30;
  float bl4[4][4], bd4[4];
#pragma unroll
  for (int g = 0; g < 4; ++g)
#pragma unroll
    for (int i = 0; i < 4; ++i) bl4[g][i] = ball[s * 512 + g * 128 + j0 + i];
#pragma unroll
  for (int i = 0; i < 4; ++i) bd4[i] = bd[s * 128 + j0 + i];

  const int ekt = j0 >> 5;
  const int elane = r | (((j0 >> 3) & 3) << 4);
  const int eoff = (ekt * 64 + elane) * 8 + (j0 & 7);

  const int rq = (l >> 4) * 4;
  const int cb = w * 64 + (l & 15);
  const int cbd = w * 16 + (l & 15);

  for (int t = 0; t < maxlen; ++t) {
    // ---- phase M: pre = h@Wall (split), pred = c@Wd ----
    f32x4 am[4], ac[4], dm;
#pragma unroll
    for (int i = 0; i < 4; ++i) { am[i] = (f32x4){0.f,0.f,0.f,0.f}; ac[i] = (f32x4){0.f,0.f,0.f,0.f}; }
    dm = (f32x4){0.f, 0.f, 0.f, 0.f};
#pragma unroll
    for (int kt = 0; kt < 4; ++kt) {
      const f16x8 ah = *(const f16x8*)&hh[(kt * 64 + l) * 8];
      const f16x8 al = *(const f16x8*)&hl[(kt * 64 + l) * 8];
      const f16x8 cf = *(const f16x8*)&chs[(kt * 64 + l) * 8];
#pragma unroll
      for (int nt = 0; nt < 4; ++nt) {
        am[nt] = __builtin_amdgcn_mfma_f32_16x16x32_f16(ah, Bh[kt * 4 + nt], am[nt], 0, 0, 0);
        ac[nt] = __builtin_amdgcn_mfma_f32_16x16x32_f16(al, Bh[kt * 4 + nt], ac[nt], 0, 0, 0);
        ac[nt] = __builtin_amdgcn_mfma_f32_16x16x32_f16(ah, Bl[kt * 4 + nt], ac[nt], 0, 0, 0);
      }
      dm = __builtin_amdgcn_mfma_f32_16x16x32_f16(cf, Dh[kt], dm, 0, 0, 0);
    }
#pragma unroll
    for (int nt = 0; nt < 4; ++nt)
#pragma unroll
      for (int qq = 0; qq < 4; ++qq)
        pre[(rq + qq) * 516 + cb + nt * 16] = am[nt][qq] + ac[nt][qq] * 4.8828125e-4f;
#pragma unroll
    for (int qq = 0; qq < 4; ++qq) pred[(rq + qq) * 132 + cbd] = dm[qq];
    __syncthreads();

    // ---- phase E: gates, state update, fragment conversion ----
    {
      const float tt = tp[t];
      const float4 cold = *(const float4*)&csm[r * 128 + j0];
      const float4 pd = *(const float4*)&pred[r * 132 + j0];
      float cs1[4];
#pragma unroll
      for (int i = 0; i < 4; ++i) cs1[i] = tanhf_(pd.x * 0.f + ((const float*)&pd)[i] + bd4[i]);
      float4 pg0 = *(const float4*)&pre[r * 516 + j0];
      float4 pg1 = *(const float4*)&pre[r * 516 + 128 + j0];
      float4 pg2 = *(const float4*)&pre[r * 516 + 256 + j0];
      float4 pg3 = *(const float4*)&pre[r * 516 + 384 + j0];
      const float4 xg0 = *(const float4*)&xu[(size_t)t * 512];
      const float4 xg1 = *(const float4*)&xu[(size_t)t * 512 + 128];
      const float4 xg2 = *(const float4*)&xu[(size_t)t * 512 + 256];
      const float4 xg3 = *(const float4*)&xu[(size_t)t * 512 + 384];
      float c2v[4], h2v[4], ov[4];
#pragma unroll
      for (int i = 0; i < 4; ++i) {
        cs1[i] = tanhf_(((const float*)&pd)[i] + bd4[i]);
        const float f  = sigf(((const float*)&pg0)[i] + ((const float*)&xg0)[i] + bl4[0][i]);
        const float ii = sigf(((const float*)&pg1)[i] + ((const float*)&xg1)[i] + bl4[1][i]);
        const float o  = sigf(((const float*)&pg2)[i] + ((const float*)&xg2)[i] + bl4[2][i]);
        const float ct = sigf(((const float*)&pg3)[i] + ((const float*)&xg3)[i] + bl4[3][i]);
        const float cc = ((const float*)&cold)[i];
        c2v[i] = f * (cc + cs1[i] * (tt - 1.f)) + ii * ct;
        h2v[i] = o * tanhf_(c2v[i]);
        ov[i] = o;
      }
      if (t < len_r) {
        float4 c2q = {c2v[0], c2v[1], c2v[2], c2v[3]};
        *(float4*)&csm[r * 128 + j0] = c2q;
        f16x4 hhi, hlo, chi;
#pragma unroll
        for (int i = 0; i < 4; ++i) {
          const _Float16 hh_ = (_Float16)h2v[i];
          hhi[i] = hh_;
          hlo[i] = (_Float16)((h2v[i] - (float)hh_) * 2048.0f);
          chi[i] = (_Float16)c2v[i];
        }
        *(f16x4*)&hh[eoff] = hhi;
        *(f16x4*)&hl[eoff] = hlo;
        *(f16x4*)&chs[eoff] = chi;
        float4 oq = {ov[0], ov[1], ov[2], ov[3]};
        *(float4*)&outp[(size_t)t * 128] = oq;
        if (t == len_r - 1) *(float4*)hnp = oq;
      }
    }
    __syncthreads();
  }
}

// ---------------------------------------------------------------------------
// K3: attention 1, per-wave t-scores.
// ---------------------------------------------------------------------------
__global__ __launch_bounds__(128) void k3_attn1(const float* __restrict__ W1,
                                                const float* __restrict__ b1,
                                                const float* __restrict__ W2,
                                                const float* __restrict__ b2,
                                                const float* __restrict__ V,
                                                const float* __restrict__ bV,
                                                const float* __restrict__ outs,
                                                const float* __restrict__ hn,
                                                const int* __restrict__ lens,
                                                float* __restrict__ ctx) {
  const int s = blockIdx.y, n = blockIdx.x, j = threadIdx.x;
  const int b = n / 5, d = n % 5;
  const int len = lens[(b * 8 + s) * 5 + d];
  __shared__ float os[30][128];
  __shared__ float hns[128];
  __shared__ float u_sh[128];
  __shared__ float score[30];

  hns[j] = hn[(size_t)(s * 160 + n) * 128 + j];
  const float* og = outs + (size_t)(s * 160 + n) * 30 * 128;
  for (int idx = j; idx < len * 128; idx += 128) (&os[0][0])[idx] = og[idx];
  __syncthreads();

  const float* W1s = W1 + (size_t)s * 16384;
  float u = b1[s * 128 + j] + b2[s * 128 + j];
  for (int k = 0; k < 128; ++k) u += hns[k] * W1s[k * 128 + j];
  u_sh[j] = u;
  __syncthreads();

  const float* W2s = W2 + (size_t)s * 16384;
  const float bVs = bV[s];
  const int lane = j & 63, wid = j >> 6;
  const float V0 = V[s * 128 + lane], V1 = V[s * 128 + 64 + lane];

  for (int t = wid; t < len; t += 2) {
    float a0 = u_sh[lane], a1 = u_sh[64 + lane];
    for (int k = 0; k < 128; ++k) {
      const float ok = os[t][k];
      a0 += ok * W2s[k * 128 + lane];
      a1 += ok * W2s[k * 128 + 64 + lane];
    }
    float p = tanhf_(a0) * V0 + tanhf_(a1) * V1;
#pragma unroll
    for (int off = 32; off; off >>= 1) p += __shfl_down(p, off);
    if (lane == 0) score[t] = p + bVs;
  }
  __syncthreads();

  float m = -1e30f;
  for (int t = 0; t < len; ++t) m = fmaxf(m, score[t]);
  float sum = 0.f;
  for (int t = 0; t < len; ++t) sum += __expf(score[t] - m);
  float cx = 0.f;
  for (int t = 0; t < len; ++t) cx += __expf(score[t] - m) * os[t][j];
  ctx[(size_t)(s * 160 + n) * 128 + j] = cx / sum;
}

// ---------------------------------------------------------------------------
// K4: LSTM over D=5, 512 threads, Whh reg-stationary. Gate order i,f,g,o.
// ---------------------------------------------------------------------------
__global__ __launch_bounds__(512) void k4_lstm2(const float* __restrict__ Wih,
                                                const float* __restrict__ bih,
                                                const float* __restrict__ Whh,
                                                const float* __restrict__ bhh,
                                                const float* __restrict__ ctx,
                                                float* __restrict__ hsout,
                                                float* __restrict__ hlast) {
  const int s = blockIdx.y, b = blockIdx.x;
  const int gj = threadIdx.x;
  __shared__ float xs[5][128];
  __shared__ float hsm[128];
  __shared__ float gsh[512];

  for (int idx = gj; idx < 640; idx += 512)
    (&xs[0][0])[idx] = ctx[(size_t)(s * 160 + b * 5) * 128 + idx];
  if (gj < 128) hsm[gj] = 0.f;
  __syncthreads();

  const float* Wis = Wih + (size_t)s * 65536;
  const float* Whs = Whh + (size_t)s * 65536;
  const float bias = bih[s * 512 + gj] + bhh[s * 512 + gj];
  float xw[5] = {bias, bias, bias, bias, bias};
  float whh[128];
#pragma unroll
  for (int k = 0; k < 128; ++k) {
    const float wi = Wis[k * 512 + gj];
    whh[k] = Whs[k * 512 + gj];
#pragma unroll
    for (int dd = 0; dd < 5; ++dd) xw[dd] += xs[dd][k] * wi;
  }

  float c = 0.f;
  for (int dd = 0; dd < 5; ++dd) {
    float g = xw[dd];
#pragma unroll
    for (int k = 0; k < 128; ++k) g += hsm[k] * whh[k];
    gsh[gj] = g;
    __syncthreads();
    if (gj < 128) {
      const int j = gj;
      const float c2 = sigf(gsh[128 + j]) * c + sigf(gsh[j]) * tanhf_(gsh[256 + j]);
      const float h2 = sigf(gsh[384 + j]) * tanhf_(c2);
      c = c2;
      hsm[j] = h2;
      hsout[((size_t)(s * 32 + b) * 5 + dd) * 128 + j] = h2;
      if (dd == 4) hlast[(size_t)(s * 32 + b) * 128 + j] = h2;
    }
    __syncthreads();
  }
}

// ---------------------------------------------------------------------------
// K5: attention 2 (no mask, D=5) + y = relu(ctx2@x1W+x1b)@x2W+x2b.
// ---------------------------------------------------------------------------
__global__ __launch_bounds__(128) void k5_attn2(const float* __restrict__ W1,
                                                const float* __restrict__ b1,
                                                const float* __restrict__ W2,
                                                const float* __restrict__ b2,
                                                const float* __restrict__ V,
                                                const float* __restrict__ bV,
                                                const float* __restrict__ x1W,
                                                const float* __restrict__ x1b,
                                                const float* __restrict__ x2W,
                                                const float* __restrict__ x2b,
                                                const float* __restrict__ hs,
                                                const float* __restrict__ hlast,
                                                float* __restrict__ y) {
  const int s = blockIdx.y, b = blockIdx.x, j = threadIdx.x;
  __shared__ float hl[128], hsm[5][128], t1[128], cs2[128], sc[5], red[2];
  hl[j] = hlast[(size_t)(s * 32 + b) * 128 + j];
  const float* hsrc = hs + (size_t)(s * 32 + b) * 640;
  for (int idx = j; idx < 640; idx += 128) (&hsm[0][0])[idx] = hsrc[idx];
  __syncthreads();

  const float* W1s = W1 + (size_t)s * 16384;
  const float* W2s = W2 + (size_t)s * 16384;
  float u = b1[s * 128 + j] + b2[s * 128 + j];
  for (int k = 0; k < 128; ++k) u += hl[k] * W1s[k * 128 + j];
  const float Vj = V[s * 128 + j];
  const int lane = j & 63, wid = j >> 6;

  for (int d = 0; d < 5; ++d) {
    float a = u;
    for (int k = 0; k < 128; ++k) a += hsm[d][k] * W2s[k * 128 + j];
    float p = tanhf_(a) * Vj;
#pragma unroll
    for (int off = 32; off; off >>= 1) p += __shfl_down(p, off);
    if (lane == 0) red[wid] = p;
    __syncthreads();
    if (j == 0) sc[d] = red[0] + red[1] + bV[s];
    __syncthreads();
  }

  float m = -1e30f;
  for (int d = 0; d < 5; ++d) m = fmaxf(m, sc[d]);
  float sum = 0.f;
  for (int d = 0; d < 5; ++d) sum += __expf(sc[d] - m);
  float cx = 0.f;
  for (int d = 0; d < 5; ++d) cx += __expf(sc[d] - m) * hsm[d][j];
  cs2[j] = cx / sum;
  __syncthreads();

  float a = x1b[s * 128 + j];
  for (int k = 0; k < 128; ++k) a += cs2[k] * x1W[(size_t)s * 16384 + k * 128 + j];
  t1[j] = fmaxf(a, 0.f);
  __syncthreads();

  if (j < 64) {
    float yy = x2b[s * 64 + j];
    for (int k = 0; k < 128; ++k) yy += t1[k] * x2W[(size_t)(s * 128 + k) * 64 + j];
    y[(size_t)(s * 32 + b) * 64 + j] = yy;
  }
}

// ---------------------------------------------------------------------------
// K6: final combine.
// ---------------------------------------------------------------------------
__global__ __launch_bounds__(256) void k6_final(const float* __restrict__ stock,
                                                const float* __restrict__ h1W,
                                                const float* __restrict__ h1b,
                                                const float* __restrict__ h2W,
                                                const float* __restrict__ h2b,
                                                const float* __restrict__ hcW,
                                                const float* __restrict__ hcb,
                                                const float* __restrict__ yws,
                                                float* __restrict__ out) {
  const int tid = threadIdx.x;
  __shared__ float sf[32 * 17];
  __shared__ float hid[32 * 64];
  __shared__ float xs[32 * 32];
  for (int idx = tid; idx < 544; idx += 256) sf[idx] = stock[idx];
  __syncthreads();
  for (int idx = tid; idx < 2048; idx += 256) {
    const int b = idx >> 6, k = idx & 63;
    float a = h1b[k];
    for (int q = 0; q < 17; ++q) a += sf[b * 17 + q] * h1W[q * 64 + k];
    hid[idx] = fmaxf(a, 0.f);
  }
  __syncthreads();
  for (int idx = tid; idx < 1024; idx += 256) {
    const int b = idx >> 5, mm = idx & 31;
    float a = h2b[mm];
    for (int k = 0; k < 64; ++k) a += hid[b * 64 + k] * h2W[k * 32 + mm];
    xs[idx] = a;
  }
  __syncthreads();
  {
    const int b = tid >> 3, o = tid & 7;
    float a = hcb[o];
    for (int c = 0; c < 32; ++c) a += xs[b * 32 + c] * hcW[c * 8 + o];
    for (int c = 32; c < 544; ++c) {
      const int ss = (c - 32) >> 6, k = (c - 32) & 63;
      a += yws[((size_t)ss * 32 + b) * 64 + k] * hcW[c * 8 + o];
    }
    out[tid] = tanhf_(a);
  }
}

// ---------------------------------------------------------------------------
extern "C" void kernel_launch(void* const* d_in, const int* in_sizes, int n_in,
                              void* d_out, int out_size, void* d_ws, size_t ws_size,
                              hipStream_t stream) {
  (void)in_sizes; (void)n_in; (void)out_size; (void)ws_size;
  const float* stock = (const float*)d_in[0];
  const float* sent  = (const float*)d_in[1];
  const float* times = (const float*)d_in[2];
  const int*   lens  = (const int*)d_in[3];
  const float* tlWall = (const float*)d_in[4];
  const float* tlball = (const float*)d_in[5];
  const float* tlUall = (const float*)d_in[6];
  const float* tlbU   = (const float*)d_in[7];
  const float* tlWd   = (const float*)d_in[8];
  const float* tlbd   = (const float*)d_in[9];
  const float* a1W1 = (const float*)d_in[10];
  const float* a1b1 = (const float*)d_in[11];
  const float* a1W2 = (const float*)d_in[12];
  const float* a1b2 = (const float*)d_in[13];
  const float* a1V  = (const float*)d_in[14];
  const float* a1bV = (const float*)d_in[15];
  const float* l2Wih = (const float*)d_in[16];
  const float* l2bih = (const float*)d_in[17];
  const float* l2Whh = (const float*)d_in[18];
  const float* l2bhh = (const float*)d_in[19];
  const float* a2W1 = (const float*)d_in[20];
  const float* a2b1 = (const float*)d_in[21];
  const float* a2W2 = (const float*)d_in[22];
  const float* a2b2 = (const float*)d_in[23];
  const float* a2V  = (const float*)d_in[24];
  const float* a2bV = (const float*)d_in[25];
  const float* x1W  = (const float*)d_in[26];
  const float* x1b  = (const float*)d_in[27];
  const float* x2W  = (const float*)d_in[28];
  const float* x2b  = (const float*)d_in[29];
  const float* h1W  = (const float*)d_in[30];
  const float* h1b  = (const float*)d_in[31];
  const float* h2W  = (const float*)d_in[32];
  const float* h2b  = (const float*)d_in[33];
  const float* hcW  = (const float*)d_in[34];
  const float* hcb  = (const float*)d_in[35];

  float* ws = (float*)d_ws;
  float* XU    = ws;               // 8*160*30*512   = 19,660,800
  float* outs  = XU + 19660800;    // 8*160*30*128   =  4,915,200
  float* hnb   = outs + 4915200;   // 8*160*128      =    163,840
  float* ctx   = hnb + 163840;     // 8*160*128      =    163,840
  float* hsb   = ctx + 163840;     // 8*32*5*128     =    163,840
  float* hlast = hsb + 163840;     // 8*32*128       =     32,768
  float* yb    = hlast + 32768;    // 8*32*64        =     16,384
  _Float16* Uhw = (_Float16*)(yb + 16384);    // 8*512*768 halfs
  _Float16* Ulw = Uhw + 8 * 512 * 768;        // 8*512*768 halfs
  _Float16* Wfh = Ulw + 8 * 512 * 768;        // 8*8*8192 halfs
  _Float16* Wfl = Wfh + 8 * 8 * 8192;         // 8*8*8192 halfs
  _Float16* Dfh = Wfl + 8 * 8 * 8192;         // 8*8*2048 halfs
  int* rowmap = (int*)(Dfh + 8 * 8 * 2048);   // 8*4800 ints
  int* Msd    = rowmap + 8 * 4800;            // 8 ints

  k0_rowmap<<<8, 256, 0, stream>>>(lens, rowmap, Msd);
  k0_usplit<<<dim3(12, 8, 8), 256, 0, stream>>>(tlUall, Uhw, Ulw);
  k0_wprep<<<dim3(8, 8), 256, 0, stream>>>(tlWall, tlWd, Wfh, Wfl, Dfh);
  k1_xu<<<dim3(152, 1, 8), 256, 0, stream>>>(sent, Uhw, Ulw, tlbU, rowmap, Msd, XU);
  k2_tlstm<<<dim3(10, 8), 512, 0, stream>>>(Wfh, Wfl, Dfh, tlball, tlbd, XU, times, lens, outs, hnb);
  k3_attn1<<<dim3(160, 8), 128, 0, stream>>>(a1W1, a1b1, a1W2, a1b2, a1V, a1bV, outs, hnb, lens, ctx);
  k4_lstm2<<<dim3(32, 8), 512, 0, stream>>>(l2Wih, l2bih, l2Whh, l2bhh, ctx, hsb, hlast);
  k5_attn2<<<dim3(32, 8), 128, 0, stream>>>(a2W1, a2b1, a2W2, a2b2, a2V, a2bV, x1W, x1b, x2W, x2b, hsb, hlast, yb);
  k6_final<<<1, 256, 0, stream>>>(stock, h1W, h1b, h2W, h2b, hcW, hcb, yb, (float*)d_out);
}

// Round 6
// 308.051 us; speedup vs baseline: 4.2803x; 1.0674x over previous
//
#include <hip/hip_runtime.h>
#include <cstddef>

// Problem constants: S=8, B=32, D=5, T=30, E=768, H=128, 4H=512.

typedef __attribute__((ext_vector_type(8))) _Float16 f16x8;
typedef __attribute__((ext_vector_type(4))) _Float16 f16x4;
typedef __attribute__((ext_vector_type(2))) _Float16 f16x2;
typedef __attribute__((ext_vector_type(4))) float f32x4;

__device__ __forceinline__ float sigf(float x) { return 1.0f / (1.0f + __expf(-x)); }
__device__ __forceinline__ float tanhf_(float x) { return 1.0f - 2.0f / (__expf(2.0f * x) + 1.0f); }

// ---------------------------------------------------------------------------
// K0r: per-stock compacted row map: rows (n,t) with t < len[s,n].
// ---------------------------------------------------------------------------
__global__ __launch_bounds__(256) void k0_rowmap(const int* __restrict__ lens,
                                                 int* __restrict__ rowmap,
                                                 int* __restrict__ Ms) {
  const int s = blockIdx.x;
  const int tid = threadIdx.x;
  __shared__ int st[160];
  __shared__ int ln[160];
  if (tid < 160) {
    const int b = tid / 5, d = tid % 5;
    ln[tid] = lens[(b * 8 + s) * 5 + d];
  }
  __syncthreads();
  if (tid == 0) {
    int run = 0;
    for (int n = 0; n < 160; ++n) { st[n] = run; run += ln[n]; }
    Ms[s] = run;
  }
  __syncthreads();
  if (tid < 160) {
    const int base = st[tid], l = ln[tid];
    for (int t = 0; t < l; ++t) rowmap[s * 4800 + base + t] = tid * 30 + t;
  }
}

// ---------------------------------------------------------------------------
// K0: split+transpose U via LDS tiles (for k1).
// ---------------------------------------------------------------------------
__global__ __launch_bounds__(256) void k0_usplit(const float* __restrict__ U,
                                                 _Float16* __restrict__ Uh,
                                                 _Float16* __restrict__ Ul) {
  const int s = blockIdx.z;
  const int k0 = blockIdx.x * 64;
  const int n0 = blockIdx.y * 64;
  const int tid = threadIdx.x;
  __shared__ _Float16 Th[64 * 66];
  __shared__ _Float16 Tl[64 * 66];
  const float* Us = U + (size_t)s * 768 * 512;
#pragma unroll
  for (int rep = 0; rep < 16; ++rep) {
    const int idx = rep * 256 + tid;
    const int r = idx >> 6, c = idx & 63;
    const float v = Us[(size_t)(k0 + r) * 512 + n0 + c];
    const _Float16 h = (_Float16)v;
    Th[r * 66 + c] = h;
    Tl[r * 66 + c] = (_Float16)((v - (float)h) * 2048.0f);
  }
  __syncthreads();
  _Float16* uhs = Uh + (size_t)s * 512 * 768;
  _Float16* uls = Ul + (size_t)s * 512 * 768;
#pragma unroll
  for (int rep = 0; rep < 8; ++rep) {
    const int idx = rep * 256 + tid;
    const int nn = idx >> 5;
    const int kp = (idx & 31) * 2;
    const f16x2 h2 = {Th[kp * 66 + nn], Th[(kp + 1) * 66 + nn]};
    const f16x2 l2 = {Tl[kp * 66 + nn], Tl[(kp + 1) * 66 + nn]};
    *(f16x2*)&uhs[(size_t)(n0 + nn) * 768 + k0 + kp] = h2;
    *(f16x2*)&uls[(size_t)(n0 + nn) * 768 + k0 + kp] = l2;
  }
}

// ---------------------------------------------------------------------------
// K0w: pack Wall (hi+lo) and Wd (hi) into MFMA B-fragment-linear layout.
//   NEW col mapping: wave w's frag-tile g covers cols n = g*128 + w*16 + (l&15)
//   so each wave owns all 4 gates for h-dims [w*16, w*16+16).
// ---------------------------------------------------------------------------
__global__ __launch_bounds__(256) void k0_wprep(const float* __restrict__ Wall,
                                                const float* __restrict__ Wd,
                                                _Float16* __restrict__ Wfh,
                                                _Float16* __restrict__ Wfl,
                                                _Float16* __restrict__ Dfh) {
  const int w = blockIdx.x, s = blockIdx.y;
  const int tid = threadIdx.x;
  const float* Ws = Wall + (size_t)s * 65536;
  _Float16* oh = Wfh + (size_t)(s * 8 + w) * 8192;
  _Float16* ol = Wfl + (size_t)(s * 8 + w) * 8192;
  for (int c = tid; c < 1024; c += 256) {
    const int kt = c >> 8, nt = (c >> 6) & 3, l = c & 63;
    const int n = nt * 128 + w * 16 + (l & 15);   // gate-major per wave
    const int kb = kt * 32 + ((l >> 4) << 3);
    f16x8 hv, lv;
#pragma unroll
    for (int e = 0; e < 8; ++e) {
      const float v = Ws[(size_t)(kb + e) * 512 + n];
      const _Float16 h = (_Float16)v;
      hv[e] = h;
      lv[e] = (_Float16)((v - (float)h) * 2048.0f);
    }
    *(f16x8*)&oh[c * 8] = hv;
    *(f16x8*)&ol[c * 8] = lv;
  }
  {
    const float* Ds = Wd + (size_t)s * 16384;
    _Float16* od = Dfh + (size_t)(s * 8 + w) * 2048;
    const int c = tid;
    const int kt = c >> 6, l = c & 63;
    const int n = w * 16 + (l & 15);
    const int kb = kt * 32 + ((l >> 4) << 3);
    f16x8 hv;
#pragma unroll
    for (int e = 0; e < 8; ++e) hv[e] = (_Float16)Ds[(size_t)(kb + e) * 128 + n];
    *(f16x8*)&od[c * 8] = hv;
  }
}

// ---------------------------------------------------------------------------
// K1 v3: XU = x @ U + bU via MFMA (unchanged from round 4).
// ---------------------------------------------------------------------------
__global__ __launch_bounds__(256, 3) void k1_xu(const float* __restrict__ sent,
                                                const _Float16* __restrict__ Uh,
                                                const _Float16* __restrict__ Ul,
                                                const float* __restrict__ bU,
                                                const int* __restrict__ rowmap,
                                                const int* __restrict__ Ms,
                                                float* __restrict__ XU) {
  const int s = blockIdx.z;
  const int M = Ms[s];
  const int nt = blockIdx.x & 3;
  const int mt = blockIdx.x >> 2;
  if (mt * 128 >= M) return;
  const int tid = threadIdx.x;
  const int lane = tid & 63, wid = tid >> 6;
  const int wm = wid >> 1, wn = wid & 1;

  __shared__ _Float16 Al[2][128 * 32];
  __shared__ _Float16 Bh[2][128 * 32];
  __shared__ _Float16 Bl[2][128 * 32];

  const int ar1 = tid >> 2;
  const int chk = tid & 3;
  const int afk = chk * 8;
  const int fw = (ar1 ^ (ar1 >> 2)) & 3;
  const int wA1 = ar1 * 32 + ((chk ^ fw) * 8);
  const int wA2 = wA1 + 64 * 32;

  const int* rms = rowmap + s * 4800;
  const float* asrc1;
  const float* asrc2;
  {
    int i1 = mt * 128 + ar1; if (i1 > M - 1) i1 = M - 1;
    const int grow = rms[i1];
    const int nn = grow / 30, tt = grow % 30, ab = nn / 5, ad = nn % 5;
    asrc1 = sent + (size_t)((((ab * 8 + s) * 5 + ad) * 30) + tt) * 768 + afk;
  }
  {
    int i2 = mt * 128 + ar1 + 64; if (i2 > M - 1) i2 = M - 1;
    const int grow = rms[i2];
    const int nn = grow / 30, tt = grow % 30, ab = nn / 5, ad = nn % 5;
    asrc2 = sent + (size_t)((((ab * 8 + s) * 5 + ad) * 30) + tt) * 768 + afk;
  }
  const _Float16* UhS = Uh + (size_t)s * 512 * 768;
  const _Float16* UlS = Ul + (size_t)s * 512 * 768;
  const _Float16* bh1 = UhS + (size_t)(nt * 128 + ar1) * 768 + afk;
  const _Float16* bh2 = UhS + (size_t)(nt * 128 + ar1 + 64) * 768 + afk;
  const _Float16* bl1 = UlS + (size_t)(nt * 128 + ar1) * 768 + afk;
  const _Float16* bl2 = UlS + (size_t)(nt * 128 + ar1 + 64) * 768 + afk;

  const _Float16 hsc = (_Float16)0.00048828125f;  // 2^-11
  const f16x8 sc8 = {hsc, hsc, hsc, hsc, hsc, hsc, hsc, hsc};

  const int q = lane >> 4;
  const int l15 = lane & 15;
  int aoff[4], boff[4];
#pragma unroll
  for (int f = 0; f < 4; ++f) {
    {
      const int row = wm * 64 + f * 16 + l15;
      const int fr = (row ^ (row >> 2)) & 3;
      aoff[f] = row * 32 + ((q ^ fr) * 8);
    }
    {
      const int row = wn * 64 + f * 16 + l15;
      const int fr = (row ^ (row >> 2)) & 3;
      boff[f] = row * 32 + ((q ^ fr) * 8);
    }
  }

  f32x4 acc[4][4];
#pragma unroll
  for (int i = 0; i < 4; ++i)
#pragma unroll
    for (int j = 0; j < 4; ++j) acc[i][j] = (f32x4){0.f, 0.f, 0.f, 0.f};

  {
    const float4 a1a = *(const float4*)(asrc1);
    const float4 a1b = *(const float4*)(asrc1 + 4);
    const float4 a2a = *(const float4*)(asrc2);
    const float4 a2b = *(const float4*)(asrc2 + 4);
    const f16x8 vh1 = *(const f16x8*)(bh1);
    const f16x8 vh2 = *(const f16x8*)(bh2);
    const f16x8 vl1 = *(const f16x8*)(bl1);
    const f16x8 vl2 = *(const f16x8*)(bl2);
    f16x8 h1, h2;
    h1[0]=(_Float16)a1a.x; h1[1]=(_Float16)a1a.y; h1[2]=(_Float16)a1a.z; h1[3]=(_Float16)a1a.w;
    h1[4]=(_Float16)a1b.x; h1[5]=(_Float16)a1b.y; h1[6]=(_Float16)a1b.z; h1[7]=(_Float16)a1b.w;
    h2[0]=(_Float16)a2a.x; h2[1]=(_Float16)a2a.y; h2[2]=(_Float16)a2a.z; h2[3]=(_Float16)a2a.w;
    h2[4]=(_Float16)a2b.x; h2[5]=(_Float16)a2b.y; h2[6]=(_Float16)a2b.z; h2[7]=(_Float16)a2b.w;
    *(f16x8*)&Al[0][wA1] = h1;
    *(f16x8*)&Al[0][wA2] = h2;
    *(f16x8*)&Bh[0][wA1] = vh1;
    *(f16x8*)&Bh[0][wA2] = vh2;
    *(f16x8*)&Bl[0][wA1] = vl1;
    *(f16x8*)&Bl[0][wA2] = vl2;
  }
  __syncthreads();

  int cur = 0;
  for (int ks = 0; ks < 24; ++ks) {
    const int nxt = cur ^ 1;
    const bool more = (ks < 23);
    float4 a1a, a1b, a2a, a2b;
    f16x8 vh1, vh2, vl1, vl2;
    if (more) {
      const int ko = (ks + 1) * 32;
      a1a = *(const float4*)(asrc1 + ko);
      a1b = *(const float4*)(asrc1 + ko + 4);
      a2a = *(const float4*)(asrc2 + ko);
      a2b = *(const float4*)(asrc2 + ko + 4);
      vh1 = *(const f16x8*)(bh1 + ko);
      vh2 = *(const f16x8*)(bh2 + ko);
      vl1 = *(const f16x8*)(bl1 + ko);
      vl2 = *(const f16x8*)(bl2 + ko);
    }
    {
      const _Float16* Ab = &Al[cur][0];
      const _Float16* Bhb = &Bh[cur][0];
      const _Float16* Blb = &Bl[cur][0];
      f16x8 af[4], asf[4], bhf[4], blf[4];
#pragma unroll
      for (int fm = 0; fm < 4; ++fm) {
        af[fm] = *(const f16x8*)&Ab[aoff[fm]];
        asf[fm] = af[fm] * sc8;
      }
#pragma unroll
      for (int fn = 0; fn < 4; ++fn) {
        bhf[fn] = *(const f16x8*)&Bhb[boff[fn]];
        blf[fn] = *(const f16x8*)&Blb[boff[fn]];
      }
#pragma unroll
      for (int fm = 0; fm < 4; ++fm)
#pragma unroll
        for (int fn = 0; fn < 4; ++fn) {
          acc[fm][fn] = __builtin_amdgcn_mfma_f32_16x16x32_f16(af[fm], bhf[fn], acc[fm][fn], 0, 0, 0);
          acc[fm][fn] = __builtin_amdgcn_mfma_f32_16x16x32_f16(asf[fm], blf[fn], acc[fm][fn], 0, 0, 0);
        }
    }
    if (more) {
      f16x8 h1, h2;
      h1[0]=(_Float16)a1a.x; h1[1]=(_Float16)a1a.y; h1[2]=(_Float16)a1a.z; h1[3]=(_Float16)a1a.w;
      h1[4]=(_Float16)a1b.x; h1[5]=(_Float16)a1b.y; h1[6]=(_Float16)a1b.z; h1[7]=(_Float16)a1b.w;
      h2[0]=(_Float16)a2a.x; h2[1]=(_Float16)a2a.y; h2[2]=(_Float16)a2a.z; h2[3]=(_Float16)a2a.w;
      h2[4]=(_Float16)a2b.x; h2[5]=(_Float16)a2b.y; h2[6]=(_Float16)a2b.z; h2[7]=(_Float16)a2b.w;
      *(f16x8*)&Al[nxt][wA1] = h1;
      *(f16x8*)&Al[nxt][wA2] = h2;
      *(f16x8*)&Bh[nxt][wA1] = vh1;
      *(f16x8*)&Bh[nxt][wA2] = vh2;
      *(f16x8*)&Bl[nxt][wA1] = vl1;
      *(f16x8*)&Bl[nxt][wA2] = vl2;
    }
    __syncthreads();
    cur = nxt;
  }

  const int lq = lane >> 4;
  const int colbase = nt * 128 + wn * 64;
  const int ibase = mt * 128 + wm * 64;
  float* XUs = XU + (size_t)s * 4800 * 512;
  int rowm[4][4];
#pragma unroll
  for (int fm = 0; fm < 4; ++fm)
#pragma unroll
    for (int r = 0; r < 4; ++r) {
      const int i = ibase + fm * 16 + lq * 4 + r;
      rowm[fm][r] = (i < M) ? rms[i] : -1;
    }
#pragma unroll
  for (int fn = 0; fn < 4; ++fn) {
    const int col = colbase + fn * 16 + l15;
    const float bias = bU[s * 512 + col];
#pragma unroll
    for (int fm = 0; fm < 4; ++fm)
#pragma unroll
      for (int r = 0; r < 4; ++r) {
        const int row = rowm[fm][r];
        if (row >= 0) XUs[(size_t)row * 512 + col] = acc[fm][fn][r] + bias;
      }
  }
}

// ---------------------------------------------------------------------------
// K2 v4: latency-lean MFMA time-LSTM. 80 blocks, 512 thr = 8 waves.
//   Wave w owns gate-major Wall cols (all 4 gates for hd in [w*16,w*16+16))
//   -> D-fragment hands each thread all 4 gate pre-acts for its (seq, hd):
//   gate math fully in registers; h,c state in registers; A-frags (h-hi,
//   h-lo, c-hi) double-buffered in LDS; ONE barrier per step.
//   Split products pre-scaled in f16 so everything accumulates into one acc.
// ---------------------------------------------------------------------------
__global__ __launch_bounds__(512) void k2_tlstm(const _Float16* __restrict__ Wfh,
                                                const _Float16* __restrict__ Wfl,
                                                const _Float16* __restrict__ Dfh,
                                                const float* __restrict__ ball,
                                                const float* __restrict__ bd,
                                                const float* __restrict__ XU,
                                                const float* __restrict__ times,
                                                const int* __restrict__ lens,
                                                float* __restrict__ outs,
                                                float* __restrict__ hn) {
  const int s = blockIdx.y;
  const int mg = blockIdx.x;
  const int tid = threadIdx.x;
  const int w = tid >> 6, l = tid & 63;

  __shared__ _Float16 hhb[2][2048];
  __shared__ _Float16 hlb[2][2048];
  __shared__ _Float16 chb[2][2048];
  __shared__ int lensh[16];

  if (tid < 16) {
    const int n = mg * 16 + tid;
    lensh[tid] = lens[((n / 5) * 8 + s) * 5 + (n % 5)];
  }

  // ---- register-stationary weight fragments ----
  f16x8 Bh[16], Bl[16], Dh[4];
  {
    const _Float16* wb = Wfh + (size_t)(s * 8 + w) * 8192 + l * 8;
    const _Float16* lb = Wfl + (size_t)(s * 8 + w) * 8192 + l * 8;
    const _Float16* db = Dfh + (size_t)(s * 8 + w) * 2048 + l * 8;
#pragma unroll
    for (int c = 0; c < 16; ++c) {
      Bh[c] = *(const f16x8*)&wb[c * 512];
      Bl[c] = *(const f16x8*)&lb[c * 512];
    }
#pragma unroll
    for (int c = 0; c < 4; ++c) Dh[c] = *(const f16x8*)&db[c * 512];
  }

  // ---- D-layout ownership: thread handles (seq rq0+q, h-dim hd), q=0..3 ----
  const int hd = w * 16 + (l & 15);
  const int rq0 = (l >> 4) * 4;
  const int lp0 = rq0 | (((hd >> 3) & 3) << 4);
  const int eoff0 = ((hd >> 5) * 64 + lp0) * 8 + (hd & 7);  // A-frag half-offset

  // zero-init buffer 0 A-frags (each thread covers its own 4 slots/array)
#pragma unroll
  for (int q = 0; q < 4; ++q) {
    hhb[0][eoff0 + q * 8] = (_Float16)0.f;
    hlb[0][eoff0 + q * 8] = (_Float16)0.f;
    chb[0][eoff0 + q * 8] = (_Float16)0.f;
  }

  int n_q[4];
  size_t xub[4];
  int tb_q[4];
#pragma unroll
  for (int q = 0; q < 4; ++q) {
    n_q[q] = mg * 16 + rq0 + q;
    xub[q] = ((size_t)(s * 160 + n_q[q])) * 30 * 512 + hd;
    tb_q[q] = (((n_q[q] / 5) * 8 + s) * 5 + (n_q[q] % 5)) * 30;
  }
  float blr[4];
#pragma unroll
  for (int g = 0; g < 4; ++g) blr[g] = ball[s * 512 + g * 128 + hd];
  const float bdj = bd[s * 128 + hd];

  __syncthreads();

  int len_q[4];
  int maxlen = 0;
#pragma unroll
  for (int i = 0; i < 16; ++i) maxlen = max(maxlen, lensh[i]);
#pragma unroll
  for (int q = 0; q < 4; ++q) len_q[q] = lensh[rq0 + q];

  const _Float16 hsc = (_Float16)0.00048828125f;  // 2^-11
  const f16x8 sc8 = {hsc, hsc, hsc, hsc, hsc, hsc, hsc, hsc};

  float creg[4] = {0.f, 0.f, 0.f, 0.f};
  float hreg[4] = {0.f, 0.f, 0.f, 0.f};

  for (int t = 0; t < maxlen; ++t) {
    const int p = t & 1;
    // ---- issue global loads early (overlap with ds_read + MFMA) ----
    float xg[4][4], tv[4];
#pragma unroll
    for (int q = 0; q < 4; ++q) {
      const float* xp = XU + xub[q] + (size_t)t * 512;
#pragma unroll
      for (int g = 0; g < 4; ++g) xg[q][g] = xp[g * 128];
      tv[q] = times[tb_q[q] + t];
    }

    // ---- M phase: one accumulator per gate (split pre-scaled in f16) ----
    f32x4 am[4], dm;
#pragma unroll
    for (int g = 0; g < 4; ++g) am[g] = (f32x4){0.f, 0.f, 0.f, 0.f};
    dm = (f32x4){0.f, 0.f, 0.f, 0.f};
#pragma unroll
    for (int kt = 0; kt < 4; ++kt) {
      const f16x8 ah = *(const f16x8*)&hhb[p][(kt * 64 + l) * 8];
      const f16x8 al = *(const f16x8*)&hlb[p][(kt * 64 + l) * 8];
      const f16x8 cf = *(const f16x8*)&chb[p][(kt * 64 + l) * 8];
      const f16x8 ahs = ah * sc8;
      const f16x8 als = al * sc8;
#pragma unroll
      for (int g = 0; g < 4; ++g) {
        am[g] = __builtin_amdgcn_mfma_f32_16x16x32_f16(ah, Bh[kt * 4 + g], am[g], 0, 0, 0);
        am[g] = __builtin_amdgcn_mfma_f32_16x16x32_f16(als, Bh[kt * 4 + g], am[g], 0, 0, 0);
        am[g] = __builtin_amdgcn_mfma_f32_16x16x32_f16(ahs, Bl[kt * 4 + g], am[g], 0, 0, 0);
      }
      dm = __builtin_amdgcn_mfma_f32_16x16x32_f16(cf, Dh[kt], dm, 0, 0, 0);
    }

    // ---- E phase: fully in-register gate math ----
#pragma unroll
    for (int q = 0; q < 4; ++q) {
      if (t < len_q[q]) {
        const float cs1 = tanhf_(dm[q] + bdj);
        const float f  = sigf(am[0][q] + xg[q][0] + blr[0]);
        const float ii = sigf(am[1][q] + xg[q][1] + blr[1]);
        const float o  = sigf(am[2][q] + xg[q][2] + blr[2]);
        const float ct = sigf(am[3][q] + xg[q][3] + blr[3]);
        const float c2 = f * (creg[q] + cs1 * (tv[q] - 1.f)) + ii * ct;
        creg[q] = c2;
        hreg[q] = o * tanhf_(c2);
        outs[((size_t)(s * 160 + n_q[q]) * 30 + t) * 128 + hd] = o;
        if (t == len_q[q] - 1) hn[(size_t)(s * 160 + n_q[q]) * 128 + hd] = o;
      }
      // unconditional frag refresh from register state (frozen seqs too)
      const _Float16 hh_ = (_Float16)hreg[q];
      hhb[p ^ 1][eoff0 + q * 8] = hh_;
      hlb[p ^ 1][eoff0 + q * 8] = (_Float16)((hreg[q] - (float)hh_) * 2048.0f);
      chb[p ^ 1][eoff0 + q * 8] = (_Float16)creg[q];
    }
    __syncthreads();
  }
}

// ---------------------------------------------------------------------------
// K3 v4: attention 1, W2 column register-stationary, no per-t barriers.
// ---------------------------------------------------------------------------
__global__ __launch_bounds__(128) void k3_attn1(const float* __restrict__ W1,
                                                const float* __restrict__ b1,
                                                const float* __restrict__ W2,
                                                const float* __restrict__ b2,
                                                const float* __restrict__ V,
                                                const float* __restrict__ bV,
                                                const float* __restrict__ outs,
                                                const float* __restrict__ hn,
                                                const int* __restrict__ lens,
                                                float* __restrict__ ctx) {
  const int s = blockIdx.y, n = blockIdx.x, j = threadIdx.x;
  const int b = n / 5, d = n % 5;
  const int len = lens[(b * 8 + s) * 5 + d];
  __shared__ float os[30][128];
  __shared__ float hns[128];
  __shared__ float swv[2][30];

  hns[j] = hn[(size_t)(s * 160 + n) * 128 + j];
  const float* og = outs + (size_t)(s * 160 + n) * 30 * 128;
  for (int idx = j; idx < len * 128; idx += 128) (&os[0][0])[idx] = og[idx];
  __syncthreads();

  // W2 column j register-stationary
  const float* W2s = W2 + (size_t)s * 16384;
  float w2r[128];
#pragma unroll
  for (int k = 0; k < 128; ++k) w2r[k] = W2s[k * 128 + j];

  const float* W1s = W1 + (size_t)s * 16384;
  float u = b1[s * 128 + j] + b2[s * 128 + j];
  for (int k = 0; k < 128; ++k) u += hns[k] * W1s[k * 128 + j];
  const float Vj = V[s * 128 + j];
  const int lane = j & 63, wid = j >> 6;

  for (int t = 0; t < len; ++t) {
    float a = u;
#pragma unroll
    for (int k4 = 0; k4 < 32; ++k4) {
      const float4 o4 = *(const float4*)&os[t][k4 * 4];
      a += o4.x * w2r[k4 * 4] + o4.y * w2r[k4 * 4 + 1] +
           o4.z * w2r[k4 * 4 + 2] + o4.w * w2r[k4 * 4 + 3];
    }
    float p = tanhf_(a) * Vj;
#pragma unroll
    for (int off = 32; off; off >>= 1) p += __shfl_down(p, off);
    if (lane == 0) swv[wid][t] = p;
  }
  __syncthreads();

  const float bVs = bV[s];
  float m = -1e30f;
  for (int t = 0; t < len; ++t) m = fmaxf(m, swv[0][t] + swv[1][t] + bVs);
  float sum = 0.f;
  for (int t = 0; t < len; ++t) sum += __expf(swv[0][t] + swv[1][t] + bVs - m);
  float cx = 0.f;
  for (int t = 0; t < len; ++t) cx += __expf(swv[0][t] + swv[1][t] + bVs - m) * os[t][j];
  ctx[(size_t)(s * 160 + n) * 128 + j] = cx / sum;
}

// ---------------------------------------------------------------------------
// K4: LSTM over D=5, 512 threads, Whh reg-stationary. Gate order i,f,g,o.
// ---------------------------------------------------------------------------
__global__ __launch_bounds__(512) void k4_lstm2(const float* __restrict__ Wih,
                                                const float* __restrict__ bih,
                                                const float* __restrict__ Whh,
                                                const float* __restrict__ bhh,
                                                const float* __restrict__ ctx,
                                                float* __restrict__ hsout,
                                                float* __restrict__ hlast) {
  const int s = blockIdx.y, b = blockIdx.x;
  const int gj = threadIdx.x;
  __shared__ float xs[5][128];
  __shared__ float hsm[128];
  __shared__ float gsh[512];

  for (int idx = gj; idx < 640; idx += 512)
    (&xs[0][0])[idx] = ctx[(size_t)(s * 160 + b * 5) * 128 + idx];
  if (gj < 128) hsm[gj] = 0.f;
  __syncthreads();

  const float* Wis = Wih + (size_t)s * 65536;
  const float* Whs = Whh + (size_t)s * 65536;
  const float bias = bih[s * 512 + gj] + bhh[s * 512 + gj];
  float xw[5] = {bias, bias, bias, bias, bias};
  float whh[128];
#pragma unroll
  for (int k = 0; k < 128; ++k) {
    const float wi = Wis[k * 512 + gj];
    whh[k] = Whs[k * 512 + gj];
#pragma unroll
    for (int dd = 0; dd < 5; ++dd) xw[dd] += xs[dd][k] * wi;
  }

  float c = 0.f;
  for (int dd = 0; dd < 5; ++dd) {
    float g = xw[dd];
#pragma unroll
    for (int k = 0; k < 128; ++k) g += hsm[k] * whh[k];
    gsh[gj] = g;
    __syncthreads();
    if (gj < 128) {
      const int j = gj;
      const float c2 = sigf(gsh[128 + j]) * c + sigf(gsh[j]) * tanhf_(gsh[256 + j]);
      const float h2 = sigf(gsh[384 + j]) * tanhf_(c2);
      c = c2;
      hsm[j] = h2;
      hsout[((size_t)(s * 32 + b) * 5 + dd) * 128 + j] = h2;
      if (dd == 4) hlast[(size_t)(s * 32 + b) * 128 + j] = h2;
    }
    __syncthreads();
  }
}

// ---------------------------------------------------------------------------
// K5: attention 2 (no mask, D=5) + y = relu(ctx2@x1W+x1b)@x2W+x2b.
// ---------------------------------------------------------------------------
__global__ __launch_bounds__(128) void k5_attn2(const float* __restrict__ W1,
                                                const float* __restrict__ b1,
                                                const float* __restrict__ W2,
                                                const float* __restrict__ b2,
                                                const float* __restrict__ V,
                                                const float* __restrict__ bV,
                                                const float* __restrict__ x1W,
                                                const float* __restrict__ x1b,
                                                const float* __restrict__ x2W,
                                                const float* __restrict__ x2b,
                                                const float* __restrict__ hs,
                                                const float* __restrict__ hlast,
                                                float* __restrict__ y) {
  const int s = blockIdx.y, b = blockIdx.x, j = threadIdx.x;
  __shared__ float hl[128], hsm[5][128], t1[128], cs2[128], sc[5], red[2];
  hl[j] = hlast[(size_t)(s * 32 + b) * 128 + j];
  const float* hsrc = hs + (size_t)(s * 32 + b) * 640;
  for (int idx = j; idx < 640; idx += 128) (&hsm[0][0])[idx] = hsrc[idx];
  __syncthreads();

  const float* W1s = W1 + (size_t)s * 16384;
  const float* W2s = W2 + (size_t)s * 16384;
  float u = b1[s * 128 + j] + b2[s * 128 + j];
  for (int k = 0; k < 128; ++k) u += hl[k] * W1s[k * 128 + j];
  const float Vj = V[s * 128 + j];
  const int lane = j & 63, wid = j >> 6;

  for (int d = 0; d < 5; ++d) {
    float a = u;
    for (int k = 0; k < 128; ++k) a += hsm[d][k] * W2s[k * 128 + j];
    float p = tanhf_(a) * Vj;
#pragma unroll
    for (int off = 32; off; off >>= 1) p += __shfl_down(p, off);
    if (lane == 0) red[wid] = p;
    __syncthreads();
    if (j == 0) sc[d] = red[0] + red[1] + bV[s];
    __syncthreads();
  }

  float m = -1e30f;
  for (int d = 0; d < 5; ++d) m = fmaxf(m, sc[d]);
  float sum = 0.f;
  for (int d = 0; d < 5; ++d) sum += __expf(sc[d] - m);
  float cx = 0.f;
  for (int d = 0; d < 5; ++d) cx += __expf(sc[d] - m) * hsm[d][j];
  cs2[j] = cx / sum;
  __syncthreads();

  float a = x1b[s * 128 + j];
  for (int k = 0; k < 128; ++k) a += cs2[k] * x1W[(size_t)s * 16384 + k * 128 + j];
  t1[j] = fmaxf(a, 0.f);
  __syncthreads();

  if (j < 64) {
    float yy = x2b[s * 64 + j];
    for (int k = 0; k < 128; ++k) yy += t1[k] * x2W[(size_t)(s * 128 + k) * 64 + j];
    y[(size_t)(s * 32 + b) * 64 + j] = yy;
  }
}

// ---------------------------------------------------------------------------
// K6: final combine.
// ---------------------------------------------------------------------------
__global__ __launch_bounds__(256) void k6_final(const float* __restrict__ stock,
                                                const float* __restrict__ h1W,
                                                const float* __restrict__ h1b,
                                                const float* __restrict__ h2W,
                                                const float* __restrict__ h2b,
                                                const float* __restrict__ hcW,
                                                const float* __restrict__ hcb,
                                                const float* __restrict__ yws,
                                                float* __restrict__ out) {
  const int tid = threadIdx.x;
  __shared__ float sf[32 * 17];
  __shared__ float hid[32 * 64];
  __shared__ float xs[32 * 32];
  for (int idx = tid; idx < 544; idx += 256) sf[idx] = stock[idx];
  __syncthreads();
  for (int idx = tid; idx < 2048; idx += 256) {
    const int b = idx >> 6, k = idx & 63;
    float a = h1b[k];
    for (int q = 0; q < 17; ++q) a += sf[b * 17 + q] * h1W[q * 64 + k];
    hid[idx] = fmaxf(a, 0.f);
  }
  __syncthreads();
  for (int idx = tid; idx < 1024; idx += 256) {
    const int b = idx >> 5, mm = idx & 31;
    float a = h2b[mm];
    for (int k = 0; k < 64; ++k) a += hid[b * 64 + k] * h2W[k * 32 + mm];
    xs[idx] = a;
  }
  __syncthreads();
  {
    const int b = tid >> 3, o = tid & 7;
    float a = hcb[o];
    for (int c = 0; c < 32; ++c) a += xs[b * 32 + c] * hcW[c * 8 + o];
    for (int c = 32; c < 544; ++c) {
      const int ss = (c - 32) >> 6, k = (c - 32) & 63;
      a += yws[((size_t)ss * 32 + b) * 64 + k] * hcW[c * 8 + o];
    }
    out[tid] = tanhf_(a);
  }
}

// ---------------------------------------------------------------------------
extern "C" void kernel_launch(void* const* d_in, const int* in_sizes, int n_in,
                              void* d_out, int out_size, void* d_ws, size_t ws_size,
                              hipStream_t stream) {
  (void)in_sizes; (void)n_in; (void)out_size; (void)ws_size;
  const float* stock = (const float*)d_in[0];
  const float* sent  = (const float*)d_in[1];
  const float* times = (const float*)d_in[2];
  const int*   lens  = (const int*)d_in[3];
  const float* tlWall = (const float*)d_in[4];
  const float* tlball = (const float*)d_in[5];
  const float* tlUall = (const float*)d_in[6];
  const float* tlbU   = (const float*)d_in[7];
  const float* tlWd   = (const float*)d_in[8];
  const float* tlbd   = (const float*)d_in[9];
  const float* a1W1 = (const float*)d_in[10];
  const float* a1b1 = (const float*)d_in[11];
  const float* a1W2 = (const float*)d_in[12];
  const float* a1b2 = (const float*)d_in[13];
  const float* a1V  = (const float*)d_in[14];
  const float* a1bV = (const float*)d_in[15];
  const float* l2Wih = (const float*)d_in[16];
  const float* l2bih = (const float*)d_in[17];
  const float* l2Whh = (const float*)d_in[18];
  const float* l2bhh = (const float*)d_in[19];
  const float* a2W1 = (const float*)d_in[20];
  const float* a2b1 = (const float*)d_in[21];
  const float* a2W2 = (const float*)d_in[22];
  const float* a2b2 = (const float*)d_in[23];
  const float* a2V  = (const float*)d_in[24];
  const float* a2bV = (const float*)d_in[25];
  const float* x1W  = (const float*)d_in[26];
  const float* x1b  = (const float*)d_in[27];
  const float* x2W  = (const float*)d_in[28];
  const float* x2b  = (const float*)d_in[29];
  const float* h1W  = (const float*)d_in[30];
  const float* h1b  = (const float*)d_in[31];
  const float* h2W  = (const float*)d_in[32];
  const float* h2b  = (const float*)d_in[33];
  const float* hcW  = (const float*)d_in[34];
  const float* hcb  = (const float*)d_in[35];

  float* ws = (float*)d_ws;
  float* XU    = ws;               // 8*160*30*512   = 19,660,800
  float* outs  = XU + 19660800;    // 8*160*30*128   =  4,915,200
  float* hnb   = outs + 4915200;   // 8*160*128      =    163,840
  float* ctx   = hnb + 163840;     // 8*160*128      =    163,840
  float* hsb   = ctx + 163840;     // 8*32*5*128     =    163,840
  float* hlast = hsb + 163840;     // 8*32*128       =     32,768
  float* yb    = hlast + 32768;    // 8*32*64        =     16,384
  _Float16* Uhw = (_Float16*)(yb + 16384);    // 8*512*768 halfs
  _Float16* Ulw = Uhw + 8 * 512 * 768;        // 8*512*768 halfs
  _Float16* Wfh = Ulw + 8 * 512 * 768;        // 8*8*8192 halfs
  _Float16* Wfl = Wfh + 8 * 8 * 8192;         // 8*8*8192 halfs
  _Float16* Dfh = Wfl + 8 * 8 * 8192;         // 8*8*2048 halfs
  int* rowmap = (int*)(Dfh + 8 * 8 * 2048);   // 8*4800 ints
  int* Msd    = rowmap + 8 * 4800;            // 8 ints

  k0_rowmap<<<8, 256, 0, stream>>>(lens, rowmap, Msd);
  k0_usplit<<<dim3(12, 8, 8), 256, 0, stream>>>(tlUall, Uhw, Ulw);
  k0_wprep<<<dim3(8, 8), 256, 0, stream>>>(tlWall, tlWd, Wfh, Wfl, Dfh);
  k1_xu<<<dim3(152, 1, 8), 256, 0, stream>>>(sent, Uhw, Ulw, tlbU, rowmap, Msd, XU);
  k2_tlstm<<<dim3(10, 8), 512, 0, stream>>>(Wfh, Wfl, Dfh, tlball, tlbd, XU, times, lens, outs, hnb);
  k3_attn1<<<dim3(160, 8), 128, 0, stream>>>(a1W1, a1b1, a1W2, a1b2, a1V, a1bV, outs, hnb, lens, ctx);
  k4_lstm2<<<dim3(32, 8), 512, 0, stream>>>(l2Wih, l2bih, l2Whh, l2bhh, ctx, hsb, hlast);
  k5_attn2<<<dim3(32, 8), 128, 0, stream>>>(a2W1, a2b1, a2W2, a2b2, a2V, a2bV, x1W, x1b, x2W, x2b, hsb, hlast, yb);
  k6_final<<<1, 256, 0, stream>>>(stock, h1W, h1b, h2W, h2b, hcW, hcb, yb, (float*)d_out);
}